// Round 5
// baseline (671.457 us; speedup 1.0000x reference)
//
#include <hip/hip_runtime.h>
#include <hip/hip_bf16.h>
#include <hip/hip_fp16.h>
#include <math.h>

// ---------------------------------------------------------------------------
// LayerNorm: one block per row (256 elems), block=256
// ---------------------------------------------------------------------------
__global__ __launch_bounds__(256) void ln_kernel(const float* __restrict__ x,
                                                 const float* __restrict__ g,
                                                 const float* __restrict__ bv,
                                                 float* __restrict__ h) {
  int row = blockIdx.x, t = threadIdx.x;
  float v = x[(size_t)row * 256 + t];
  float s = v, q = v * v;
#pragma unroll
  for (int o = 32; o > 0; o >>= 1) {
    s += __shfl_xor(s, o);
    q += __shfl_xor(q, o);
  }
  __shared__ float ss[4], qq[4];
  int w = t >> 6, l = t & 63;
  if (l == 0) { ss[w] = s; qq[w] = q; }
  __syncthreads();
  s = ss[0] + ss[1] + ss[2] + ss[3];
  q = qq[0] + qq[1] + qq[2] + qq[3];
  float mu = s * (1.f / 256.f);
  float var = q * (1.f / 256.f) - mu * mu;
  float inv = rsqrtf(var + 1e-5f);
  h[(size_t)row * 256 + t] = (v - mu) * inv * g[t] + bv[t];
}

// ---------------------------------------------------------------------------
// Tiled fp32 GEMM: C[M,N] = A[M,K] @ B[K,N] (+ bias[n]); BM=BN=64, BK=16
// ---------------------------------------------------------------------------
__global__ __launch_bounds__(256) void gemm_kernel(const float* __restrict__ A,
                                                   const float* __restrict__ Bm,
                                                   const float* __restrict__ bias,
                                                   float* __restrict__ C,
                                                   int M, int N, int K) {
  const int BK = 16;
  __shared__ float As[BK][64];
  __shared__ float Bs[BK][64];
  int tx = threadIdx.x & 15, ty = threadIdx.x >> 4;
  int m0 = blockIdx.y * 64, n0 = blockIdx.x * 64;
  float acc[4][4] = {};
  for (int k0 = 0; k0 < K; k0 += BK) {
    {
      int r = threadIdx.x >> 2;
      int c4 = (threadIdx.x & 3) * 4;
      float4 a = *(const float4*)&A[(size_t)(m0 + r) * K + k0 + c4];
      As[c4 + 0][r] = a.x; As[c4 + 1][r] = a.y;
      As[c4 + 2][r] = a.z; As[c4 + 3][r] = a.w;
    }
    {
      int kk = threadIdx.x >> 4;
      int c4 = (threadIdx.x & 15) * 4;
      *(float4*)&Bs[kk][c4] = *(const float4*)&Bm[(size_t)(k0 + kk) * N + n0 + c4];
    }
    __syncthreads();
#pragma unroll
    for (int kk = 0; kk < BK; kk++) {
      float a[4], bb[4];
#pragma unroll
      for (int r = 0; r < 4; r++) a[r] = As[kk][ty * 4 + r];
#pragma unroll
      for (int c = 0; c < 4; c++) bb[c] = Bs[kk][tx * 4 + c];
#pragma unroll
      for (int r = 0; r < 4; r++)
#pragma unroll
        for (int c = 0; c < 4; c++) acc[r][c] = fmaf(a[r], bb[c], acc[r][c]);
    }
    __syncthreads();
  }
#pragma unroll
  for (int r = 0; r < 4; r++) {
    int row = m0 + ty * 4 + r;
#pragma unroll
    for (int c = 0; c < 4; c++) {
      int col = n0 + tx * 4 + c;
      float val = acc[r][c] + (bias ? bias[col] : 0.f);
      C[(size_t)row * N + col] = val;
    }
  }
}

// ---------------------------------------------------------------------------
// RoPE + split qkv (2048 x 768) -> q,k,v in (B,H,N,D) layout
// ---------------------------------------------------------------------------
__global__ __launch_bounds__(256) void rope_split(const float* __restrict__ qkv,
                                                  float* __restrict__ qo,
                                                  float* __restrict__ ko,
                                                  float* __restrict__ vo) {
  int row = blockIdx.x;           // b*1024 + n
  int b = row >> 10, n = row & 1023;
  int t = threadIdx.x;            // h*32 + d
  int hh = t >> 5, d = t & 31;
  const float* base = qkv + (size_t)row * 768;
  float vv = base[512 + t];
  int f = d & 15;
  float inv_freq = powf(10000.0f, -(float)f / 16.0f);
  float ang = (float)n * inv_freq;
  float sn, cs;
  sincosf(ang, &sn, &cs);
  float q1 = base[hh * 32 + f], q2 = base[hh * 32 + f + 16];
  float k1 = base[256 + hh * 32 + f], k2 = base[256 + hh * 32 + f + 16];
  float qr = (d < 16) ? (q1 * cs - q2 * sn) : (q2 * cs + q1 * sn);
  float kr = (d < 16) ? (k1 * cs - k2 * sn) : (k2 * cs + k1 * sn);
  size_t oidx = ((size_t)(b * 8 + hh) * 1024 + n) * 32 + d;
  qo[oidx] = qr;
  ko[oidx] = kr;
  vo[oidx] = vv;
}

// ---------------------------------------------------------------------------
// Fast exact GELU via Abramowitz-Stegun 7.1.26 erf (max err 1.5e-7)
// ---------------------------------------------------------------------------
__device__ __forceinline__ float gelu_fast(float z) {
  float s = z * 0.70710678118654752f;
  float a = fabsf(s);
  float t = __builtin_amdgcn_rcpf(fmaf(0.3275911f, a, 1.0f));
  float poly = t * fmaf(t, fmaf(t, fmaf(t, fmaf(t, 1.061405429f, -1.453152027f),
                                        1.421413741f),
                                -0.284496736f),
                        0.254829592f);
  float e = __expf(-a * a);
  float erf_a = fmaf(-poly, e, 1.0f);
  float erf_s = copysignf(erf_a, s);
  return 0.5f * z * (1.0f + erf_s);
}

// ---------------------------------------------------------------------------
// Relational bias MLP -> rel[b][h][i][jrel] (fp16), jrel = j - j_base.
// grid = 2 * 128 * (jspan/64) blocks, 256 threads (th=i 0..7, tl=j-pair 0..31).
// ---------------------------------------------------------------------------
__global__ __launch_bounds__(256) void rel_kernel(
    const float* __restrict__ coords, const float* __restrict__ vels,
    const float* __restrict__ w1, const float* __restrict__ b1,
    const float* __restrict__ w2, const float* __restrict__ b2,
    __half* __restrict__ rel, int j_base, int jspan) {
  const int bx = blockIdx.x;
  const int it = bx & 127;
  const int rest = bx >> 7;
  const int nj = jspan >> 6;
  const int jt = rest % nj;
  const int b = rest / nj;
  const int t = threadIdx.x;
  const int th = t >> 5, tl = t & 31;
  const int i = it * 8 + th;
  const int j = j_base + jt * 64 + 2 * tl;

  __shared__ float pack[64][16];  // per-k: w1[0..4][k], b1[k], w2[k][0..7], pad
  {
    int kk = t & 63, f = t >> 6;
    float4 val;
    if (f == 0)
      val = make_float4(w1[kk], w1[64 + kk], w1[128 + kk], w1[192 + kk]);
    else if (f == 1)
      val = make_float4(w1[256 + kk], b1[kk], w2[kk * 8], w2[kk * 8 + 1]);
    else if (f == 2)
      val = make_float4(w2[kk * 8 + 2], w2[kk * 8 + 3], w2[kk * 8 + 4], w2[kk * 8 + 5]);
    else
      val = make_float4(w2[kk * 8 + 6], w2[kk * 8 + 7], 0.f, 0.f);
    *(float4*)&pack[kk][f * 4] = val;
  }
  float2 ci = *(const float2*)&coords[(size_t)(b * 1024 + i) * 2];
  float2 vi = *(const float2*)&vels[(size_t)(b * 1024 + i) * 2];
  float4 cj = *(const float4*)&coords[(size_t)(b * 1024 + j) * 2];  // j and j+1
  float4 vj = *(const float4*)&vels[(size_t)(b * 1024 + j) * 2];
  float dx0a = ci.x - cj.x, dx1a = ci.y - cj.y;
  float dx0b = ci.x - cj.z, dx1b = ci.y - cj.w;
  float dv0a = vi.x - vj.x, dv1a = vi.y - vj.y;
  float dv0b = vi.x - vj.z, dv1b = vi.y - vj.w;
  float dista = sqrtf(dx0a * dx0a + dx1a * dx1a);
  float distb = sqrtf(dx0b * dx0b + dx1b * dx1b);
  float relA[8], relB[8];
#pragma unroll
  for (int h = 0; h < 8; h++) { relA[h] = b2[h]; relB[h] = relA[h]; }
  __syncthreads();

#pragma unroll 4
  for (int kk = 0; kk < 64; kk++) {
    float4 p0 = *(float4*)&pack[kk][0];
    float4 p1 = *(float4*)&pack[kk][4];
    float4 p2 = *(float4*)&pack[kk][8];
    float4 p3 = *(float4*)&pack[kk][12];
    float za = fmaf(dx0a, p0.x, fmaf(dx1a, p0.y, fmaf(dista, p0.z,
               fmaf(dv0a, p0.w, fmaf(dv1a, p1.x, p1.y)))));
    float zb = fmaf(dx0b, p0.x, fmaf(dx1b, p0.y, fmaf(distb, p0.z,
               fmaf(dv0b, p0.w, fmaf(dv1b, p1.x, p1.y)))));
    float ga = gelu_fast(za);
    float gb = gelu_fast(zb);
    relA[0] = fmaf(ga, p1.z, relA[0]);  relB[0] = fmaf(gb, p1.z, relB[0]);
    relA[1] = fmaf(ga, p1.w, relA[1]);  relB[1] = fmaf(gb, p1.w, relB[1]);
    relA[2] = fmaf(ga, p2.x, relA[2]);  relB[2] = fmaf(gb, p2.x, relB[2]);
    relA[3] = fmaf(ga, p2.y, relA[3]);  relB[3] = fmaf(gb, p2.y, relB[3]);
    relA[4] = fmaf(ga, p2.z, relA[4]);  relB[4] = fmaf(gb, p2.z, relB[4]);
    relA[5] = fmaf(ga, p2.w, relA[5]);  relB[5] = fmaf(gb, p2.w, relB[5]);
    relA[6] = fmaf(ga, p3.x, relA[6]);  relB[6] = fmaf(gb, p3.x, relB[6]);
    relA[7] = fmaf(ga, p3.y, relA[7]);  relB[7] = fmaf(gb, p3.y, relB[7]);
  }
  size_t jrel = (size_t)(j - j_base);
#pragma unroll
  for (int h = 0; h < 8; h++) {
    __half2 hv = __halves2half2(__float2half_rn(relA[h]), __float2half_rn(relB[h]));
    *(__half2*)&rel[((size_t)(b * 8 + h) * 1024 + i) * jspan + jrel] = hv;
  }
}

// ---------------------------------------------------------------------------
// Attention, wave-independent: block = (b, h, i-group-of-8), 4 waves = 4
// j-subranges of jspan/4. ONE barrier (Q staging); then each wave runs
// j-tiles of 64 with lane=j (scores+softmax) and lane=(i-quad,d) for PV,
// exchanging P through a private LDS slice (wave-internal ordering, no bar).
// init=1: start (m,l,O) fresh; init=0: merge with existing partials.
// ---------------------------------------------------------------------------
__global__ __launch_bounds__(256) void attn_kernel(
    const float* __restrict__ q, const float* __restrict__ k,
    const float* __restrict__ v, const __half* __restrict__ rel,
    int j_base, int jspan, int init,
    float* __restrict__ Opart, float* __restrict__ ml) {
  const int ig = blockIdx.x & 127;
  const int h  = (blockIdx.x >> 7) & 7;
  const int b  = blockIdx.x >> 10;
  const int i0 = ig * 8;
  const int t  = threadIdx.x;
  const int wv = t >> 6;        // j-subrange / partial slot
  const int lane = t & 63;
  const int ih = lane >> 5, d = lane & 31;

  __shared__ float Qs[8][32];
  __shared__ float pS[4][64][12];   // [wave][j][i(8) + pad4]; 48B rows, aligned

  {
    int i = t >> 5, dd = t & 31;
    Qs[i][dd] = q[((size_t)(b * 8 + h) * 1024 + i0 + i) * 32 + dd];
  }
  __syncthreads();

  const float scale = 0.17677669529663687f;  // 1/sqrt(32)
  const size_t bh = (size_t)(b * 8 + h) * 1024;
  const int sub = jspan >> 2;
  const int jlo = j_base + wv * sub;

  float m[8], l[8];
  float O0, O1, O2, O3;
  size_t obase = ((size_t)(b * 4 + wv) * 1024 + i0) * 256 + h * 32 + d;
  if (init) {
#pragma unroll
    for (int i = 0; i < 8; i++) { m[i] = -1e30f; l[i] = 0.f; }
    O0 = O1 = O2 = O3 = 0.f;
  } else {
#pragma unroll
    for (int i = 0; i < 8; i++) {
      float2 mlv = ((const float2*)ml)[((size_t)(b * 4 + wv) * 1024 + i0 + i) * 8 + h];
      m[i] = mlv.x; l[i] = mlv.y;
    }
    O0 = Opart[obase + (ih * 4 + 0) * 256];
    O1 = Opart[obase + (ih * 4 + 1) * 256];
    O2 = Opart[obase + (ih * 4 + 2) * 256];
    O3 = Opart[obase + (ih * 4 + 3) * 256];
  }

  for (int jt = jlo; jt < jlo + sub; jt += 64) {
    // ---- scores + online softmax: lane = j ----
    const int j = jt + lane;
    float rv[8];
#pragma unroll
    for (int i = 0; i < 8; i++)
      rv[i] = __half2float(rel[(bh + i0 + i) * (size_t)jspan + (j - j_base)]);
    const float* krow = k + (bh + j) * 32;
    float4 kr0 = *(const float4*)(krow + 0);
    float4 kr1 = *(const float4*)(krow + 4);
    float4 kr2 = *(const float4*)(krow + 8);
    float4 kr3 = *(const float4*)(krow + 12);
    float4 kr4 = *(const float4*)(krow + 16);
    float4 kr5 = *(const float4*)(krow + 20);
    float4 kr6 = *(const float4*)(krow + 24);
    float4 kr7 = *(const float4*)(krow + 28);
    float s[8];
#pragma unroll
    for (int i = 0; i < 8; i++) s[i] = 0.f;
#define DOT_E(KR, E)                                                          \
  _Pragma("unroll")                                                           \
  for (int i = 0; i < 8; i++) {                                               \
    float4 qv = *(const float4*)&Qs[i][(E) * 4];                              \
    s[i] = fmaf(qv.x, KR.x, fmaf(qv.y, KR.y,                                  \
           fmaf(qv.z, KR.z, fmaf(qv.w, KR.w, s[i]))));                        \
  }
    DOT_E(kr0, 0) DOT_E(kr1, 1) DOT_E(kr2, 2) DOT_E(kr3, 3)
    DOT_E(kr4, 4) DOT_E(kr5, 5) DOT_E(kr6, 6) DOT_E(kr7, 7)
#undef DOT_E
    float f[8], pp[8];
#pragma unroll
    for (int i = 0; i < 8; i++) {
      float sv = fmaf(s[i], scale, rv[i]);
      float tm = sv;
#pragma unroll
      for (int o = 32; o > 0; o >>= 1) tm = fmaxf(tm, __shfl_xor(tm, o));
      float nm = fmaxf(m[i], tm);
      float fc = __expf(m[i] - nm);
      float p = __expf(sv - nm);
      float ts = p;
#pragma unroll
      for (int o = 32; o > 0; o >>= 1) ts += __shfl_xor(ts, o);
      m[i] = nm;
      l[i] = l[i] * fc + ts;
      f[i] = fc;
      pp[i] = p;
    }
    *(float4*)&pS[wv][lane][0] = make_float4(pp[0], pp[1], pp[2], pp[3]);
    *(float4*)&pS[wv][lane][4] = make_float4(pp[4], pp[5], pp[6], pp[7]);
    // ---- PV: lane = (ih, d); i = ih*4 + kk ----
    float f0 = ih ? f[4] : f[0];
    float f1 = ih ? f[5] : f[1];
    float f2 = ih ? f[6] : f[2];
    float f3 = ih ? f[7] : f[3];
    float a0 = 0.f, a1 = 0.f, a2 = 0.f, a3 = 0.f;
    const float* vbase = v + (bh + jt) * 32 + d;
#pragma unroll 8
    for (int jj = 0; jj < 64; jj++) {
      float4 p4 = *(const float4*)&pS[wv][jj][ih * 4];
      float vv = vbase[(size_t)jj * 32];
      a0 = fmaf(p4.x, vv, a0);
      a1 = fmaf(p4.y, vv, a1);
      a2 = fmaf(p4.z, vv, a2);
      a3 = fmaf(p4.w, vv, a3);
    }
    O0 = fmaf(O0, f0, a0);
    O1 = fmaf(O1, f1, a1);
    O2 = fmaf(O2, f2, a2);
    O3 = fmaf(O3, f3, a3);
  }
  Opart[obase + (ih * 4 + 0) * 256] = O0;
  Opart[obase + (ih * 4 + 1) * 256] = O1;
  Opart[obase + (ih * 4 + 2) * 256] = O2;
  Opart[obase + (ih * 4 + 3) * 256] = O3;
  if (lane == 0) {
#pragma unroll
    for (int i = 0; i < 8; i++)
      ((float2*)ml)[((size_t)(b * 4 + wv) * 1024 + i0 + i) * 8 + h] =
          make_float2(m[i], l[i]);
  }
}

// ---------------------------------------------------------------------------
// Combine j-split partials: grid = 256 blocks (b, i-group of 8), 256 threads.
// ---------------------------------------------------------------------------
__global__ __launch_bounds__(256) void combine_kernel(
    const float* __restrict__ Opart, const float* __restrict__ ml,
    float* __restrict__ attn) {
  int b = blockIdx.x >> 7, ig = blockIdx.x & 127;
  int i0 = ig * 8;
  int t = threadIdx.x, hh = t >> 5;
#pragma unroll
  for (int i = 0; i < 8; i++) {
    float2 mls[4];
    float M = -1e30f;
#pragma unroll
    for (int js = 0; js < 4; js++) {
      mls[js] = ((const float2*)ml)[(((size_t)(b * 4 + js) * 1024) + i0 + i) * 8 + hh];
      M = fmaxf(M, mls[js].x);
    }
    float L = 0.f, Ov = 0.f;
#pragma unroll
    for (int js = 0; js < 4; js++) {
      float w = __expf(mls[js].x - M);
      L += mls[js].y * w;
      Ov += Opart[(((size_t)(b * 4 + js) * 1024) + i0 + i) * 256 + t] * w;
    }
    attn[((size_t)b * 1024 + i0 + i) * 256 + t] = Ov / L;
  }
}

// ---------------------------------------------------------------------------
extern "C" void kernel_launch(void* const* d_in, const int* in_sizes, int n_in,
                              void* d_out, int out_size, void* d_ws, size_t ws_size,
                              hipStream_t stream) {
  const float* x      = (const float*)d_in[0];
  const float* coords = (const float*)d_in[1];
  const float* vels   = (const float*)d_in[2];
  const float* ln_g   = (const float*)d_in[3];
  const float* ln_b   = (const float*)d_in[4];
  const float* w_qkv  = (const float*)d_in[5];
  const float* w_o    = (const float*)d_in[6];
  const float* b_o    = (const float*)d_in[7];
  const float* w1     = (const float*)d_in[8];
  const float* b1     = (const float*)d_in[9];
  const float* w2     = (const float*)d_in[10];
  const float* b2     = (const float*)d_in[11];
  float* out = (float*)d_out;

  float* ws    = (float*)d_ws;
  float* h_ln  = ws;                  // 524288 floats (dead after qkv gemm)
  float* qkv   = ws + 524288;         // 1572864 floats (dead after rope)
  float* Opart = ws;                  // 2097152 floats, reuses h_ln+qkv
  float* qb    = ws + 2097152;
  float* kb    = qb + 524288;
  float* vb    = kb + 524288;
  float* attn  = vb + 524288;         // ends at float 4194304 = byte 16777216
  __half* relh = (__half*)((char*)d_ws + 16777216);
  float* ml    = (float*)d_out;       // 131072 floats scratch; final gemm
                                      // fully rewrites d_out afterwards

  ln_kernel<<<2048, 256, 0, stream>>>(x, ln_g, ln_b, h_ln);
  gemm_kernel<<<dim3(12, 32), 256, 0, stream>>>(h_ln, w_qkv, nullptr, qkv, 2048, 768, 256);
  rope_split<<<2048, 256, 0, stream>>>(qkv, qb, kb, vb);

  const size_t full_bytes = 16777216ull + 2ull * 8 * 1024 * 1024 * 2;  // 50.3 MB
  if (ws_size >= full_bytes) {
    rel_kernel<<<2 * 128 * 16, 256, 0, stream>>>(coords, vels, w1, b1, w2, b2,
                                                 relh, 0, 1024);
    attn_kernel<<<2048, 256, 0, stream>>>(qb, kb, vb, relh, 0, 1024, 1, Opart, ml);
  } else {
    for (int c = 0; c < 4; c++) {
      rel_kernel<<<2 * 128 * 4, 256, 0, stream>>>(coords, vels, w1, b1, w2, b2,
                                                  relh, c * 256, 256);
      attn_kernel<<<2048, 256, 0, stream>>>(qb, kb, vb, relh, c * 256, 256,
                                            c == 0 ? 1 : 0, Opart, ml);
    }
  }
  combine_kernel<<<256, 256, 0, stream>>>(Opart, ml, attn);
  gemm_kernel<<<dim3(4, 32), 256, 0, stream>>>(attn, w_o, b_o, out, 2048, 256, 256);
}

// Round 6
// 174.300 us; speedup vs baseline: 3.8523x; 3.8523x over previous
//
#include <hip/hip_runtime.h>
#include <hip/hip_bf16.h>
#include <hip/hip_fp16.h>
#include <math.h>

typedef _Float16 half8 __attribute__((ext_vector_type(8)));
typedef _Float16 half4 __attribute__((ext_vector_type(4)));
typedef float floatx4 __attribute__((ext_vector_type(4)));

#if defined(__has_builtin) && __has_builtin(__builtin_amdgcn_mfma_f32_16x16x16f16)
#define MFMA_PV(a, b, c) __builtin_amdgcn_mfma_f32_16x16x16f16((a), (b), (c), 0, 0, 0)
#else
__device__ __forceinline__ floatx4 mfma_pv_asm(half4 a, half4 b, floatx4 c) {
  floatx4 d;
  asm volatile("v_mfma_f32_16x16x16_f16 %0, %1, %2, %3"
               : "=v"(d) : "v"(a), "v"(b), "v"(c));
  return d;
}
#define MFMA_PV(a, b, c) mfma_pv_asm((a), (b), (c))
#endif

// ---------------------------------------------------------------------------
// LayerNorm: one block per row (256 elems), block=256
// ---------------------------------------------------------------------------
__global__ __launch_bounds__(256) void ln_kernel(const float* __restrict__ x,
                                                 const float* __restrict__ g,
                                                 const float* __restrict__ bv,
                                                 float* __restrict__ h) {
  int row = blockIdx.x, t = threadIdx.x;
  float v = x[(size_t)row * 256 + t];
  float s = v, q = v * v;
#pragma unroll
  for (int o = 32; o > 0; o >>= 1) {
    s += __shfl_xor(s, o);
    q += __shfl_xor(q, o);
  }
  __shared__ float ss[4], qq[4];
  int w = t >> 6, l = t & 63;
  if (l == 0) { ss[w] = s; qq[w] = q; }
  __syncthreads();
  s = ss[0] + ss[1] + ss[2] + ss[3];
  q = qq[0] + qq[1] + qq[2] + qq[3];
  float mu = s * (1.f / 256.f);
  float var = q * (1.f / 256.f) - mu * mu;
  float inv = rsqrtf(var + 1e-5f);
  h[(size_t)row * 256 + t] = (v - mu) * inv * g[t] + bv[t];
}

// ---------------------------------------------------------------------------
// Tiled fp32 GEMM: C[M,N] = A[M,K] @ B[K,N] (+ bias[n]); BM=BN=64, BK=16
// ---------------------------------------------------------------------------
__global__ __launch_bounds__(256) void gemm_kernel(const float* __restrict__ A,
                                                   const float* __restrict__ Bm,
                                                   const float* __restrict__ bias,
                                                   float* __restrict__ C,
                                                   int M, int N, int K) {
  const int BK = 16;
  __shared__ float As[BK][64];
  __shared__ float Bs[BK][64];
  int tx = threadIdx.x & 15, ty = threadIdx.x >> 4;
  int m0 = blockIdx.y * 64, n0 = blockIdx.x * 64;
  float acc[4][4] = {};
  for (int k0 = 0; k0 < K; k0 += BK) {
    {
      int r = threadIdx.x >> 2;
      int c4 = (threadIdx.x & 3) * 4;
      float4 a = *(const float4*)&A[(size_t)(m0 + r) * K + k0 + c4];
      As[c4 + 0][r] = a.x; As[c4 + 1][r] = a.y;
      As[c4 + 2][r] = a.z; As[c4 + 3][r] = a.w;
    }
    {
      int kk = threadIdx.x >> 4;
      int c4 = (threadIdx.x & 15) * 4;
      *(float4*)&Bs[kk][c4] = *(const float4*)&Bm[(size_t)(k0 + kk) * N + n0 + c4];
    }
    __syncthreads();
#pragma unroll
    for (int kk = 0; kk < BK; kk++) {
      float a[4], bb[4];
#pragma unroll
      for (int r = 0; r < 4; r++) a[r] = As[kk][ty * 4 + r];
#pragma unroll
      for (int c = 0; c < 4; c++) bb[c] = Bs[kk][tx * 4 + c];
#pragma unroll
      for (int r = 0; r < 4; r++)
#pragma unroll
        for (int c = 0; c < 4; c++) acc[r][c] = fmaf(a[r], bb[c], acc[r][c]);
    }
    __syncthreads();
  }
#pragma unroll
  for (int r = 0; r < 4; r++) {
    int row = m0 + ty * 4 + r;
#pragma unroll
    for (int c = 0; c < 4; c++) {
      int col = n0 + tx * 4 + c;
      float val = acc[r][c] + (bias ? bias[col] : 0.f);
      C[(size_t)row * N + col] = val;
    }
  }
}

// ---------------------------------------------------------------------------
// RoPE + split qkv (2048 x 768) -> q,k,v FP16 in (B,H,N,D) layout
// ---------------------------------------------------------------------------
__global__ __launch_bounds__(256) void rope_split(const float* __restrict__ qkv,
                                                  __half* __restrict__ qo,
                                                  __half* __restrict__ ko,
                                                  __half* __restrict__ vo) {
  int row = blockIdx.x;           // b*1024 + n
  int b = row >> 10, n = row & 1023;
  int t = threadIdx.x;            // h*32 + d
  int hh = t >> 5, d = t & 31;
  const float* base = qkv + (size_t)row * 768;
  float vv = base[512 + t];
  int f = d & 15;
  float inv_freq = powf(10000.0f, -(float)f / 16.0f);
  float ang = (float)n * inv_freq;
  float sn, cs;
  sincosf(ang, &sn, &cs);
  float q1 = base[hh * 32 + f], q2 = base[hh * 32 + f + 16];
  float k1 = base[256 + hh * 32 + f], k2 = base[256 + hh * 32 + f + 16];
  float qr = (d < 16) ? (q1 * cs - q2 * sn) : (q2 * cs + q1 * sn);
  float kr = (d < 16) ? (k1 * cs - k2 * sn) : (k2 * cs + k1 * sn);
  size_t oidx = ((size_t)(b * 8 + hh) * 1024 + n) * 32 + d;
  qo[oidx] = __float2half_rn(qr);
  ko[oidx] = __float2half_rn(kr);
  vo[oidx] = __float2half_rn(vv);
}

// ---------------------------------------------------------------------------
// Fast exact GELU via Abramowitz-Stegun 7.1.26 erf (max err 1.5e-7)
// ---------------------------------------------------------------------------
__device__ __forceinline__ float gelu_fast(float z) {
  float s = z * 0.70710678118654752f;
  float a = fabsf(s);
  float t = __builtin_amdgcn_rcpf(fmaf(0.3275911f, a, 1.0f));
  float poly = t * fmaf(t, fmaf(t, fmaf(t, fmaf(t, 1.061405429f, -1.453152027f),
                                        1.421413741f),
                                -0.284496736f),
                        0.254829592f);
  float e = __expf(-a * a);
  float erf_a = fmaf(-poly, e, 1.0f);
  float erf_s = copysignf(erf_a, s);
  return 0.5f * z * (1.0f + erf_s);
}

// ---------------------------------------------------------------------------
// Relational bias MLP -> rel[b][h][jrel][i] (fp16), TRANSPOSED layout.
// Block = (b, j-octet within jspan, i-tile of 64); thread th=j(8), tl=i-pair.
// grid = 2 * (jspan/8) * 16 blocks, 256 threads.
// ---------------------------------------------------------------------------
__global__ __launch_bounds__(256) void rel_kernel(
    const float* __restrict__ coords, const float* __restrict__ vels,
    const float* __restrict__ w1, const float* __restrict__ b1,
    const float* __restrict__ w2, const float* __restrict__ b2,
    __half* __restrict__ rel, int j_base, int jspan) {
  const int bx = blockIdx.x;
  const int itile = bx & 15;
  const int rest = bx >> 4;
  const int njg = jspan >> 3;
  const int jg = rest % njg;
  const int b = rest / njg;
  const int t = threadIdx.x;
  const int th = t >> 5, tl = t & 31;
  const int j = j_base + jg * 8 + th;
  const int i = itile * 64 + 2 * tl;

  __shared__ float pack[64][16];  // per-k: w1[0..4][k], b1[k], w2[k][0..7], pad
  {
    int kk = t & 63, f = t >> 6;
    float4 val;
    if (f == 0)
      val = make_float4(w1[kk], w1[64 + kk], w1[128 + kk], w1[192 + kk]);
    else if (f == 1)
      val = make_float4(w1[256 + kk], b1[kk], w2[kk * 8], w2[kk * 8 + 1]);
    else if (f == 2)
      val = make_float4(w2[kk * 8 + 2], w2[kk * 8 + 3], w2[kk * 8 + 4], w2[kk * 8 + 5]);
    else
      val = make_float4(w2[kk * 8 + 6], w2[kk * 8 + 7], 0.f, 0.f);
    *(float4*)&pack[kk][f * 4] = val;
  }
  float2 cj = *(const float2*)&coords[(size_t)(b * 1024 + j) * 2];
  float2 vj = *(const float2*)&vels[(size_t)(b * 1024 + j) * 2];
  float4 ci = *(const float4*)&coords[(size_t)(b * 1024 + i) * 2];  // i, i+1
  float4 vi = *(const float4*)&vels[(size_t)(b * 1024 + i) * 2];
  // dx = coords_i - coords_j (i = query)
  float dx0a = ci.x - cj.x, dx1a = ci.y - cj.y;
  float dx0b = ci.z - cj.x, dx1b = ci.w - cj.y;
  float dv0a = vi.x - vj.x, dv1a = vi.y - vj.y;
  float dv0b = vi.z - vj.x, dv1b = vi.w - vj.y;
  float dista = sqrtf(dx0a * dx0a + dx1a * dx1a);
  float distb = sqrtf(dx0b * dx0b + dx1b * dx1b);
  float relA[8], relB[8];
#pragma unroll
  for (int h = 0; h < 8; h++) { relA[h] = b2[h]; relB[h] = relA[h]; }
  __syncthreads();

#pragma unroll 4
  for (int kk = 0; kk < 64; kk++) {
    float4 p0 = *(float4*)&pack[kk][0];
    float4 p1 = *(float4*)&pack[kk][4];
    float4 p2 = *(float4*)&pack[kk][8];
    float4 p3 = *(float4*)&pack[kk][12];
    float za = fmaf(dx0a, p0.x, fmaf(dx1a, p0.y, fmaf(dista, p0.z,
               fmaf(dv0a, p0.w, fmaf(dv1a, p1.x, p1.y)))));
    float zb = fmaf(dx0b, p0.x, fmaf(dx1b, p0.y, fmaf(distb, p0.z,
               fmaf(dv0b, p0.w, fmaf(dv1b, p1.x, p1.y)))));
    float ga = gelu_fast(za);
    float gb = gelu_fast(zb);
    relA[0] = fmaf(ga, p1.z, relA[0]);  relB[0] = fmaf(gb, p1.z, relB[0]);
    relA[1] = fmaf(ga, p1.w, relA[1]);  relB[1] = fmaf(gb, p1.w, relB[1]);
    relA[2] = fmaf(ga, p2.x, relA[2]);  relB[2] = fmaf(gb, p2.x, relB[2]);
    relA[3] = fmaf(ga, p2.y, relA[3]);  relB[3] = fmaf(gb, p2.y, relB[3]);
    relA[4] = fmaf(ga, p2.z, relA[4]);  relB[4] = fmaf(gb, p2.z, relB[4]);
    relA[5] = fmaf(ga, p2.w, relA[5]);  relB[5] = fmaf(gb, p2.w, relB[5]);
    relA[6] = fmaf(ga, p3.x, relA[6]);  relB[6] = fmaf(gb, p3.x, relB[6]);
    relA[7] = fmaf(ga, p3.y, relA[7]);  relB[7] = fmaf(gb, p3.y, relB[7]);
  }
#pragma unroll
  for (int h = 0; h < 8; h++) {
    __half2 hv = __halves2half2(__float2half_rn(relA[h]), __float2half_rn(relB[h]));
    *(__half2*)&rel[((size_t)(b * 8 + h) * jspan + (j - j_base)) * 1024 + i] = hv;
  }
}

// ---------------------------------------------------------------------------
// MFMA flash attention. One wave = (b, h, i-tile of 16, j-quarter of 256).
// S^T = mfma_16x16x32_f16(K-frag, Q-frag): lane l&15 = i -> softmax reduction
// is 3 in-lane fmax + 2 shuffles. P stays in-lane as the A-frag of
// PV = mfma_16x16x16_f16(P, V). No LDS, no barriers.
// js_force < 0: full (4 j-quarters, grid 1024); else chunked (grid 256).
// ---------------------------------------------------------------------------
__global__ __launch_bounds__(256) void attn_mfma(
    const __half* __restrict__ qh, const __half* __restrict__ kh,
    const __half* __restrict__ vh, const __half* __restrict__ rel,
    int j_base, int jspan, int js_force,
    float* __restrict__ Opart, float* __restrict__ ml) {
  const int task = blockIdx.x * 4 + (threadIdx.x >> 6);
  int js, it, h, b;
  if (js_force >= 0) {
    js = js_force; it = task & 63; h = (task >> 6) & 7; b = task >> 9;
  } else {
    js = task & 3; it = (task >> 2) & 63; h = (task >> 8) & 7; b = task >> 11;
  }
  const int lane = threadIdx.x & 63;
  const int lg = lane >> 4;   // k-block / j-subrow group
  const int li = lane & 15;   // i (softmax) / col index
  const int i0 = it * 16;
  const size_t bh = (size_t)(b * 8 + h) * 1024;
  const float scale = 0.17677669529663687f;  // 1/sqrt(32)

  // Q fragment (B operand): Q[i0+li][8*lg .. +7]
  const half8 qf = *(const half8*)((const _Float16*)qh + (bh + i0 + li) * 32 + 8 * lg);

  floatx4 accLo = {0.f, 0.f, 0.f, 0.f};
  floatx4 accHi = {0.f, 0.f, 0.f, 0.f};
  float m_run = -3.0e38f, l_run = 0.f;

  for (int jt = js * 256; jt < js * 256 + 256; jt += 16) {
    // K fragment (A operand): K[jt+li][8*lg .. +7]
    half8 kf = *(const half8*)((const _Float16*)kh + (bh + jt + li) * 32 + 8 * lg);
    floatx4 zero = {0.f, 0.f, 0.f, 0.f};
    floatx4 st = __builtin_amdgcn_mfma_f32_16x16x32_f16(kf, qf, zero, 0, 0, 0);
    // st[r] = S[i = i0+li][j = jt + 4*lg + r]
    const __half* rrow = rel + ((size_t)(b * 8 + h) * jspan + (jt - j_base + 4 * lg)) * 1024 + i0 + li;
    float s0 = fmaf(st[0], scale, __half2float(rrow[0]));
    float s1 = fmaf(st[1], scale, __half2float(rrow[1024]));
    float s2 = fmaf(st[2], scale, __half2float(rrow[2048]));
    float s3 = fmaf(st[3], scale, __half2float(rrow[3072]));
    // online softmax over the 16 j of this tile (per i = li)
    float tm = fmaxf(fmaxf(s0, s1), fmaxf(s2, s3));
    tm = fmaxf(tm, __shfl_xor(tm, 16));
    tm = fmaxf(tm, __shfl_xor(tm, 32));
    float nm = fmaxf(m_run, tm);
    float fc = __expf(m_run - nm);
    float p0 = __expf(s0 - nm);
    float p1 = __expf(s1 - nm);
    float p2 = __expf(s2 - nm);
    float p3 = __expf(s3 - nm);
    float ts = (p0 + p1) + (p2 + p3);
    ts += __shfl_xor(ts, 16);
    ts += __shfl_xor(ts, 32);
    l_run = l_run * fc + ts;
    m_run = nm;
    // rescale O: acc rows are i = i0 + 4*lg + r -> fetch fc from lane 4*lg+r
    float fT0 = __shfl(fc, 4 * lg + 0);
    float fT1 = __shfl(fc, 4 * lg + 1);
    float fT2 = __shfl(fc, 4 * lg + 2);
    float fT3 = __shfl(fc, 4 * lg + 3);
    accLo[0] *= fT0; accHi[0] *= fT0;
    accLo[1] *= fT1; accHi[1] *= fT1;
    accLo[2] *= fT2; accHi[2] *= fT2;
    accLo[3] *= fT3; accHi[3] *= fT3;
    // P fragment (A operand of PV): A[m=li][k=4*lg+q] = p_q  -- already in-lane
    half4 pf;
    pf[0] = (_Float16)p0; pf[1] = (_Float16)p1;
    pf[2] = (_Float16)p2; pf[3] = (_Float16)p3;
    // V fragments (B operand): V[jt + 4*lg + q][d], d = li / li+16
    const _Float16* vb = (const _Float16*)vh + (bh + jt + 4 * lg) * 32 + li;
    half4 vf0, vf1;
    vf0[0] = vb[0];  vf0[1] = vb[32]; vf0[2] = vb[64]; vf0[3] = vb[96];
    vf1[0] = vb[16]; vf1[1] = vb[48]; vf1[2] = vb[80]; vf1[3] = vb[112];
    accLo = MFMA_PV(pf, vf0, accLo);
    accHi = MFMA_PV(pf, vf1, accHi);
  }
  // write partials: O rows i = i0 + 4*lg + r, cols h*32 + li (+16)
  size_t orow = (size_t)(b * 4 + js) * 1024 + i0 + 4 * lg;
#pragma unroll
  for (int r = 0; r < 4; r++) {
    float* op = Opart + (orow + r) * 256 + h * 32 + li;
    op[0] = accLo[r];
    op[16] = accHi[r];
  }
  if (lane < 16) {
    ((float2*)ml)[((size_t)(b * 4 + js) * 1024 + i0 + lane) * 8 + h] =
        make_float2(m_run, l_run);
  }
}

// ---------------------------------------------------------------------------
// Combine j-split partials: grid = 256 blocks (b, i-group of 8), 256 threads.
// ---------------------------------------------------------------------------
__global__ __launch_bounds__(256) void combine_kernel(
    const float* __restrict__ Opart, const float* __restrict__ ml,
    float* __restrict__ attn) {
  int b = blockIdx.x >> 7, ig = blockIdx.x & 127;
  int i0 = ig * 8;
  int t = threadIdx.x, hh = t >> 5;
#pragma unroll
  for (int i = 0; i < 8; i++) {
    float2 mls[4];
    float M = -1e30f;
#pragma unroll
    for (int js = 0; js < 4; js++) {
      mls[js] = ((const float2*)ml)[(((size_t)(b * 4 + js) * 1024) + i0 + i) * 8 + hh];
      M = fmaxf(M, mls[js].x);
    }
    float L = 0.f, Ov = 0.f;
#pragma unroll
    for (int js = 0; js < 4; js++) {
      float w = __expf(mls[js].x - M);
      L += mls[js].y * w;
      Ov += Opart[(((size_t)(b * 4 + js) * 1024) + i0 + i) * 256 + t] * w;
    }
    attn[((size_t)b * 1024 + i0 + i) * 256 + t] = Ov / L;
  }
}

// ---------------------------------------------------------------------------
extern "C" void kernel_launch(void* const* d_in, const int* in_sizes, int n_in,
                              void* d_out, int out_size, void* d_ws, size_t ws_size,
                              hipStream_t stream) {
  const float* x      = (const float*)d_in[0];
  const float* coords = (const float*)d_in[1];
  const float* vels   = (const float*)d_in[2];
  const float* ln_g   = (const float*)d_in[3];
  const float* ln_b   = (const float*)d_in[4];
  const float* w_qkv  = (const float*)d_in[5];
  const float* w_o    = (const float*)d_in[6];
  const float* b_o    = (const float*)d_in[7];
  const float* w1     = (const float*)d_in[8];
  const float* b1     = (const float*)d_in[9];
  const float* w2     = (const float*)d_in[10];
  const float* b2     = (const float*)d_in[11];
  float* out = (float*)d_out;

  // ws layout (bytes):
  //  [0, 2MB)    h_ln (fp32, dead after qkv gemm)      \ reused as Opart
  //  [2MB, 8MB)  qkv  (fp32, dead after rope)          /  [0, 8MB) fp32
  //  [8MB, 9MB)  qh fp16   [9,10) kh   [10,11) vh
  //  [11MB,13MB) attn fp32
  //  [13MB, ...) rel fp16: full 32MB -> ends 45MB; chunk 8MB -> ends 21MB
  float* ws    = (float*)d_ws;
  float* h_ln  = ws;
  float* qkv   = ws + 524288;
  float* Opart = ws;
  __half* qh   = (__half*)((char*)d_ws + 8388608);
  __half* kh   = qh + 524288;
  __half* vh   = kh + 524288;
  float* attn  = (float*)((char*)d_ws + 11534336);
  __half* relh = (__half*)((char*)d_ws + 13631488);
  float* ml    = (float*)d_out;  // scratch; final gemm fully rewrites d_out

  ln_kernel<<<2048, 256, 0, stream>>>(x, ln_g, ln_b, h_ln);
  gemm_kernel<<<dim3(12, 32), 256, 0, stream>>>(h_ln, w_qkv, nullptr, qkv, 2048, 768, 256);
  rope_split<<<2048, 256, 0, stream>>>(qkv, qh, kh, vh);

  const size_t full_bytes = 13631488ull + 2ull * 8 * 1024 * 1024 * 2;  // 45 MB
  if (ws_size >= full_bytes) {
    rel_kernel<<<2 * 128 * 16, 256, 0, stream>>>(coords, vels, w1, b1, w2, b2,
                                                 relh, 0, 1024);
    attn_mfma<<<1024, 256, 0, stream>>>(qh, kh, vh, relh, 0, 1024, -1, Opart, ml);
  } else {
    for (int c = 0; c < 4; c++) {
      rel_kernel<<<2 * 32 * 16, 256, 0, stream>>>(coords, vels, w1, b1, w2, b2,
                                                  relh, c * 256, 256);
      attn_mfma<<<256, 256, 0, stream>>>(qh, kh, vh, relh, c * 256, 256, c,
                                         Opart, ml);
    }
  }
  combine_kernel<<<256, 256, 0, stream>>>(Opart, ml, attn);
  gemm_kernel<<<dim3(4, 32), 256, 0, stream>>>(attn, w_o, b_o, out, 2048, 256, 256);
}

// Round 7
// 164.804 us; speedup vs baseline: 4.0743x; 1.0576x over previous
//
#include <hip/hip_runtime.h>
#include <hip/hip_bf16.h>
#include <hip/hip_fp16.h>
#include <math.h>

typedef _Float16 half8 __attribute__((ext_vector_type(8)));
typedef _Float16 half4 __attribute__((ext_vector_type(4)));
typedef float floatx4 __attribute__((ext_vector_type(4)));
typedef float f2 __attribute__((ext_vector_type(2)));

#if defined(__has_builtin) && __has_builtin(__builtin_amdgcn_mfma_f32_16x16x16f16)
#define MFMA_PV(a, b, c) __builtin_amdgcn_mfma_f32_16x16x16f16((a), (b), (c), 0, 0, 0)
#else
__device__ __forceinline__ floatx4 mfma_pv_asm(half4 a, half4 b, floatx4 c) {
  floatx4 d;
  asm volatile("v_mfma_f32_16x16x16_f16 %0, %1, %2, %3"
               : "=v"(d) : "v"(a), "v"(b), "v"(c));
  return d;
}
#define MFMA_PV(a, b, c) mfma_pv_asm((a), (b), (c))
#endif

// ---------------------------------------------------------------------------
// LayerNorm: one block per row (256 elems), block=256
// ---------------------------------------------------------------------------
__global__ __launch_bounds__(256) void ln_kernel(const float* __restrict__ x,
                                                 const float* __restrict__ g,
                                                 const float* __restrict__ bv,
                                                 float* __restrict__ h) {
  int row = blockIdx.x, t = threadIdx.x;
  float v = x[(size_t)row * 256 + t];
  float s = v, q = v * v;
#pragma unroll
  for (int o = 32; o > 0; o >>= 1) {
    s += __shfl_xor(s, o);
    q += __shfl_xor(q, o);
  }
  __shared__ float ss[4], qq[4];
  int w = t >> 6, l = t & 63;
  if (l == 0) { ss[w] = s; qq[w] = q; }
  __syncthreads();
  s = ss[0] + ss[1] + ss[2] + ss[3];
  q = qq[0] + qq[1] + qq[2] + qq[3];
  float mu = s * (1.f / 256.f);
  float var = q * (1.f / 256.f) - mu * mu;
  float inv = rsqrtf(var + 1e-5f);
  h[(size_t)row * 256 + t] = (v - mu) * inv * g[t] + bv[t];
}

// ---------------------------------------------------------------------------
// Tiled fp32 GEMM: C[M,N] = A[M,K] @ B[K,N] (+ bias[n]); BM=BN=64, BK=16
// ---------------------------------------------------------------------------
__global__ __launch_bounds__(256) void gemm_kernel(const float* __restrict__ A,
                                                   const float* __restrict__ Bm,
                                                   const float* __restrict__ bias,
                                                   float* __restrict__ C,
                                                   int M, int N, int K) {
  const int BK = 16;
  __shared__ float As[BK][64];
  __shared__ float Bs[BK][64];
  int tx = threadIdx.x & 15, ty = threadIdx.x >> 4;
  int m0 = blockIdx.y * 64, n0 = blockIdx.x * 64;
  float acc[4][4] = {};
  for (int k0 = 0; k0 < K; k0 += BK) {
    {
      int r = threadIdx.x >> 2;
      int c4 = (threadIdx.x & 3) * 4;
      float4 a = *(const float4*)&A[(size_t)(m0 + r) * K + k0 + c4];
      As[c4 + 0][r] = a.x; As[c4 + 1][r] = a.y;
      As[c4 + 2][r] = a.z; As[c4 + 3][r] = a.w;
    }
    {
      int kk = threadIdx.x >> 4;
      int c4 = (threadIdx.x & 15) * 4;
      *(float4*)&Bs[kk][c4] = *(const float4*)&Bm[(size_t)(k0 + kk) * N + n0 + c4];
    }
    __syncthreads();
#pragma unroll
    for (int kk = 0; kk < BK; kk++) {
      float a[4], bb[4];
#pragma unroll
      for (int r = 0; r < 4; r++) a[r] = As[kk][ty * 4 + r];
#pragma unroll
      for (int c = 0; c < 4; c++) bb[c] = Bs[kk][tx * 4 + c];
#pragma unroll
      for (int r = 0; r < 4; r++)
#pragma unroll
        for (int c = 0; c < 4; c++) acc[r][c] = fmaf(a[r], bb[c], acc[r][c]);
    }
    __syncthreads();
  }
#pragma unroll
  for (int r = 0; r < 4; r++) {
    int row = m0 + ty * 4 + r;
#pragma unroll
    for (int c = 0; c < 4; c++) {
      int col = n0 + tx * 4 + c;
      float val = acc[r][c] + (bias ? bias[col] : 0.f);
      C[(size_t)row * N + col] = val;
    }
  }
}

// ---------------------------------------------------------------------------
// RoPE + split qkv (2048 x 768) -> q,k,v FP16 in (B,H,N,D) layout
// ---------------------------------------------------------------------------
__global__ __launch_bounds__(256) void rope_split(const float* __restrict__ qkv,
                                                  __half* __restrict__ qo,
                                                  __half* __restrict__ ko,
                                                  __half* __restrict__ vo) {
  int row = blockIdx.x;           // b*1024 + n
  int b = row >> 10, n = row & 1023;
  int t = threadIdx.x;            // h*32 + d
  int hh = t >> 5, d = t & 31;
  const float* base = qkv + (size_t)row * 768;
  float vv = base[512 + t];
  int f = d & 15;
  float inv_freq = powf(10000.0f, -(float)f / 16.0f);
  float ang = (float)n * inv_freq;
  float sn, cs;
  sincosf(ang, &sn, &cs);
  float q1 = base[hh * 32 + f], q2 = base[hh * 32 + f + 16];
  float k1 = base[256 + hh * 32 + f], k2 = base[256 + hh * 32 + f + 16];
  float qr = (d < 16) ? (q1 * cs - q2 * sn) : (q2 * cs + q1 * sn);
  float kr = (d < 16) ? (k1 * cs - k2 * sn) : (k2 * cs + k1 * sn);
  size_t oidx = ((size_t)(b * 8 + hh) * 1024 + n) * 32 + d;
  qo[oidx] = __float2half_rn(qr);
  ko[oidx] = __float2half_rn(kr);
  vo[oidx] = __float2half_rn(vv);
}

// ---------------------------------------------------------------------------
// Packed-fp32 exact GELU (A-S 7.1.26 erf, max err 1.5e-7), two values/call.
// gelu(z) = 0.5z + 0.5|z| - 0.5|z|*poly(t)*exp(-s^2),  s = z/sqrt(2)
// (sign-free reformulation; algebraically equal to 0.5z(1+erf(s)).)
// ---------------------------------------------------------------------------
__device__ __forceinline__ f2 gelu2(f2 z) {
  f2 az = __builtin_elementwise_max(z, -z);          // |z|   (v_pk_max)
  f2 a = az * 0.70710678118654752f;                  // |s|
  f2 ta = a * 0.3275911f + 1.0f;
  f2 t;
  t.x = __builtin_amdgcn_rcpf(ta.x);
  t.y = __builtin_amdgcn_rcpf(ta.y);
  f2 poly = ((((t * 1.061405429f + -1.453152027f) * t + 1.421413741f) * t +
              -0.284496736f) * t + 0.254829592f) * t;
  f2 a2 = a * a;
  f2 e;
  e.x = __expf(-a2.x);
  e.y = __expf(-a2.y);
  f2 haz = az * 0.5f;
  return (z * 0.5f + haz) - haz * (poly * e);
}

// ---------------------------------------------------------------------------
// Relational bias MLP -> rel[b][h][jrel][i] (fp16), TRANSPOSED layout.
// Block = (b, j-octet within jspan, i-tile of 64); thread th=j(8), tl=i-pair.
// The two i's of a thread are computed PACKED in <2 x float> so the whole
// z/gelu/w2 chain lowers to v_pk_* (2 FMA per instruction).
// grid = 2 * (jspan/8) * 16 blocks, 256 threads.
// ---------------------------------------------------------------------------
__global__ __launch_bounds__(256) void rel_kernel(
    const float* __restrict__ coords, const float* __restrict__ vels,
    const float* __restrict__ w1, const float* __restrict__ b1,
    const float* __restrict__ w2, const float* __restrict__ b2,
    __half* __restrict__ rel, int j_base, int jspan) {
  const int bx = blockIdx.x;
  const int itile = bx & 15;
  const int rest = bx >> 4;
  const int njg = jspan >> 3;
  const int jg = rest % njg;
  const int b = rest / njg;
  const int t = threadIdx.x;
  const int th = t >> 5, tl = t & 31;
  const int j = j_base + jg * 8 + th;
  const int i = itile * 64 + 2 * tl;

  __shared__ float pack[64][16];  // per-k: w1[0..4][k], b1[k], w2[k][0..7], pad
  {
    int kk = t & 63, f = t >> 6;
    float4 val;
    if (f == 0)
      val = make_float4(w1[kk], w1[64 + kk], w1[128 + kk], w1[192 + kk]);
    else if (f == 1)
      val = make_float4(w1[256 + kk], b1[kk], w2[kk * 8], w2[kk * 8 + 1]);
    else if (f == 2)
      val = make_float4(w2[kk * 8 + 2], w2[kk * 8 + 3], w2[kk * 8 + 4], w2[kk * 8 + 5]);
    else
      val = make_float4(w2[kk * 8 + 6], w2[kk * 8 + 7], 0.f, 0.f);
    *(float4*)&pack[kk][f * 4] = val;
  }
  float2 cj = *(const float2*)&coords[(size_t)(b * 1024 + j) * 2];
  float2 vj = *(const float2*)&vels[(size_t)(b * 1024 + j) * 2];
  float4 ci = *(const float4*)&coords[(size_t)(b * 1024 + i) * 2];  // i, i+1
  float4 vi = *(const float4*)&vels[(size_t)(b * 1024 + i) * 2];
  // packed diffs: component 0 = pair (i, j), component 1 = pair (i+1, j)
  f2 dx0 = {ci.x - cj.x, ci.z - cj.x};
  f2 dx1 = {ci.y - cj.y, ci.w - cj.y};
  f2 dv0 = {vi.x - vj.x, vi.z - vj.x};
  f2 dv1 = {vi.y - vj.y, vi.w - vj.y};
  f2 d2 = dx0 * dx0 + dx1 * dx1;
  f2 dist = {sqrtf(d2.x), sqrtf(d2.y)};
  f2 relv[8];
#pragma unroll
  for (int h = 0; h < 8; h++) {
    float bb = b2[h];
    relv[h] = (f2){bb, bb};
  }
  __syncthreads();

#pragma unroll 2
  for (int kk = 0; kk < 64; kk++) {
    float4 p0 = *(float4*)&pack[kk][0];
    float4 p1 = *(float4*)&pack[kk][4];
    float4 p2 = *(float4*)&pack[kk][8];
    float4 p3 = *(float4*)&pack[kk][12];
    f2 z = dv1 * p1.x + p1.y;
    z = dv0 * p0.w + z;
    z = dist * p0.z + z;
    z = dx1 * p0.y + z;
    z = dx0 * p0.x + z;
    f2 g = gelu2(z);
    relv[0] = g * p1.z + relv[0];
    relv[1] = g * p1.w + relv[1];
    relv[2] = g * p2.x + relv[2];
    relv[3] = g * p2.y + relv[3];
    relv[4] = g * p2.z + relv[4];
    relv[5] = g * p2.w + relv[5];
    relv[6] = g * p3.x + relv[6];
    relv[7] = g * p3.y + relv[7];
  }
#pragma unroll
  for (int h = 0; h < 8; h++) {
    __half2 hv = __halves2half2(__float2half_rn(relv[h].x),
                                __float2half_rn(relv[h].y));
    *(__half2*)&rel[((size_t)(b * 8 + h) * jspan + (j - j_base)) * 1024 + i] = hv;
  }
}

// ---------------------------------------------------------------------------
// MFMA flash attention. One wave = (b, h, i-tile of 16, j-quarter of 256).
// S^T = mfma_16x16x32_f16(K-frag, Q-frag): lane l&15 = i -> softmax reduction
// is 3 in-lane fmax + 2 shuffles. P stays in-lane as the A-frag of
// PV = mfma_16x16x16_f16(P, V). No LDS, no barriers.
// js_force < 0: full (4 j-quarters, grid 1024); else chunked (grid 256).
// ---------------------------------------------------------------------------
__global__ __launch_bounds__(256) void attn_mfma(
    const __half* __restrict__ qh, const __half* __restrict__ kh,
    const __half* __restrict__ vh, const __half* __restrict__ rel,
    int j_base, int jspan, int js_force,
    float* __restrict__ Opart, float* __restrict__ ml) {
  const int task = blockIdx.x * 4 + (threadIdx.x >> 6);
  int js, it, h, b;
  if (js_force >= 0) {
    js = js_force; it = task & 63; h = (task >> 6) & 7; b = task >> 9;
  } else {
    js = task & 3; it = (task >> 2) & 63; h = (task >> 8) & 7; b = task >> 11;
  }
  const int lane = threadIdx.x & 63;
  const int lg = lane >> 4;   // k-block / j-subrow group
  const int li = lane & 15;   // i (softmax) / col index
  const int i0 = it * 16;
  const size_t bh = (size_t)(b * 8 + h) * 1024;
  const float scale = 0.17677669529663687f;  // 1/sqrt(32)

  // Q fragment (B operand): Q[i0+li][8*lg .. +7]
  const half8 qf = *(const half8*)((const _Float16*)qh + (bh + i0 + li) * 32 + 8 * lg);

  floatx4 accLo = {0.f, 0.f, 0.f, 0.f};
  floatx4 accHi = {0.f, 0.f, 0.f, 0.f};
  float m_run = -3.0e38f, l_run = 0.f;

  for (int jt = js * 256; jt < js * 256 + 256; jt += 16) {
    // K fragment (A operand): K[jt+li][8*lg .. +7]
    half8 kf = *(const half8*)((const _Float16*)kh + (bh + jt + li) * 32 + 8 * lg);
    floatx4 zero = {0.f, 0.f, 0.f, 0.f};
    floatx4 st = __builtin_amdgcn_mfma_f32_16x16x32_f16(kf, qf, zero, 0, 0, 0);
    // st[r] = S[i = i0+li][j = jt + 4*lg + r]
    const __half* rrow = rel + ((size_t)(b * 8 + h) * jspan + (jt - j_base + 4 * lg)) * 1024 + i0 + li;
    float s0 = fmaf(st[0], scale, __half2float(rrow[0]));
    float s1 = fmaf(st[1], scale, __half2float(rrow[1024]));
    float s2 = fmaf(st[2], scale, __half2float(rrow[2048]));
    float s3 = fmaf(st[3], scale, __half2float(rrow[3072]));
    // online softmax over the 16 j of this tile (per i = li)
    float tm = fmaxf(fmaxf(s0, s1), fmaxf(s2, s3));
    tm = fmaxf(tm, __shfl_xor(tm, 16));
    tm = fmaxf(tm, __shfl_xor(tm, 32));
    float nm = fmaxf(m_run, tm);
    float fc = __expf(m_run - nm);
    float p0 = __expf(s0 - nm);
    float p1 = __expf(s1 - nm);
    float p2 = __expf(s2 - nm);
    float p3 = __expf(s3 - nm);
    float ts = (p0 + p1) + (p2 + p3);
    ts += __shfl_xor(ts, 16);
    ts += __shfl_xor(ts, 32);
    l_run = l_run * fc + ts;
    m_run = nm;
    // rescale O: acc rows are i = i0 + 4*lg + r -> fetch fc from lane 4*lg+r
    float fT0 = __shfl(fc, 4 * lg + 0);
    float fT1 = __shfl(fc, 4 * lg + 1);
    float fT2 = __shfl(fc, 4 * lg + 2);
    float fT3 = __shfl(fc, 4 * lg + 3);
    accLo[0] *= fT0; accHi[0] *= fT0;
    accLo[1] *= fT1; accHi[1] *= fT1;
    accLo[2] *= fT2; accHi[2] *= fT2;
    accLo[3] *= fT3; accHi[3] *= fT3;
    // P fragment (A operand of PV): A[m=li][k=4*lg+q] = p_q  -- already in-lane
    half4 pf;
    pf[0] = (_Float16)p0; pf[1] = (_Float16)p1;
    pf[2] = (_Float16)p2; pf[3] = (_Float16)p3;
    // V fragments (B operand): V[jt + 4*lg + q][d], d = li / li+16
    const _Float16* vb = (const _Float16*)vh + (bh + jt + 4 * lg) * 32 + li;
    half4 vf0, vf1;
    vf0[0] = vb[0];  vf0[1] = vb[32]; vf0[2] = vb[64]; vf0[3] = vb[96];
    vf1[0] = vb[16]; vf1[1] = vb[48]; vf1[2] = vb[80]; vf1[3] = vb[112];
    accLo = MFMA_PV(pf, vf0, accLo);
    accHi = MFMA_PV(pf, vf1, accHi);
  }
  // write partials: O rows i = i0 + 4*lg + r, cols h*32 + li (+16)
  size_t orow = (size_t)(b * 4 + js) * 1024 + i0 + 4 * lg;
#pragma unroll
  for (int r = 0; r < 4; r++) {
    float* op = Opart + (orow + r) * 256 + h * 32 + li;
    op[0] = accLo[r];
    op[16] = accHi[r];
  }
  if (lane < 16) {
    ((float2*)ml)[((size_t)(b * 4 + js) * 1024 + i0 + lane) * 8 + h] =
        make_float2(m_run, l_run);
  }
}

// ---------------------------------------------------------------------------
// Combine j-split partials: grid = 256 blocks (b, i-group of 8), 256 threads.
// ---------------------------------------------------------------------------
__global__ __launch_bounds__(256) void combine_kernel(
    const float* __restrict__ Opart, const float* __restrict__ ml,
    float* __restrict__ attn) {
  int b = blockIdx.x >> 7, ig = blockIdx.x & 127;
  int i0 = ig * 8;
  int t = threadIdx.x, hh = t >> 5;
#pragma unroll
  for (int i = 0; i < 8; i++) {
    float2 mls[4];
    float M = -1e30f;
#pragma unroll
    for (int js = 0; js < 4; js++) {
      mls[js] = ((const float2*)ml)[(((size_t)(b * 4 + js) * 1024) + i0 + i) * 8 + hh];
      M = fmaxf(M, mls[js].x);
    }
    float L = 0.f, Ov = 0.f;
#pragma unroll
    for (int js = 0; js < 4; js++) {
      float w = __expf(mls[js].x - M);
      L += mls[js].y * w;
      Ov += Opart[(((size_t)(b * 4 + js) * 1024) + i0 + i) * 256 + t] * w;
    }
    attn[((size_t)b * 1024 + i0 + i) * 256 + t] = Ov / L;
  }
}

// ---------------------------------------------------------------------------
extern "C" void kernel_launch(void* const* d_in, const int* in_sizes, int n_in,
                              void* d_out, int out_size, void* d_ws, size_t ws_size,
                              hipStream_t stream) {
  const float* x      = (const float*)d_in[0];
  const float* coords = (const float*)d_in[1];
  const float* vels   = (const float*)d_in[2];
  const float* ln_g   = (const float*)d_in[3];
  const float* ln_b   = (const float*)d_in[4];
  const float* w_qkv  = (const float*)d_in[5];
  const float* w_o    = (const float*)d_in[6];
  const float* b_o    = (const float*)d_in[7];
  const float* w1     = (const float*)d_in[8];
  const float* b1     = (const float*)d_in[9];
  const float* w2     = (const float*)d_in[10];
  const float* b2     = (const float*)d_in[11];
  float* out = (float*)d_out;

  // ws layout (bytes):
  //  [0, 2MB)    h_ln (fp32, dead after qkv gemm)      \ reused as Opart
  //  [2MB, 8MB)  qkv  (fp32, dead after rope)          /  [0, 8MB) fp32
  //  [8MB, 9MB)  qh fp16   [9,10) kh   [10,11) vh
  //  [11MB,13MB) attn fp32
  //  [13MB, ...) rel fp16: full 32MB -> ends 45MB; chunk 8MB -> ends 21MB
  float* ws    = (float*)d_ws;
  float* h_ln  = ws;
  float* qkv   = ws + 524288;
  float* Opart = ws;
  __half* qh   = (__half*)((char*)d_ws + 8388608);
  __half* kh   = qh + 524288;
  __half* vh   = kh + 524288;
  float* attn  = (float*)((char*)d_ws + 11534336);
  __half* relh = (__half*)((char*)d_ws + 13631488);
  float* ml    = (float*)d_out;  // scratch; final gemm fully rewrites d_out

  ln_kernel<<<2048, 256, 0, stream>>>(x, ln_g, ln_b, h_ln);
  gemm_kernel<<<dim3(12, 32), 256, 0, stream>>>(h_ln, w_qkv, nullptr, qkv, 2048, 768, 256);
  rope_split<<<2048, 256, 0, stream>>>(qkv, qh, kh, vh);

  const size_t full_bytes = 13631488ull + 2ull * 8 * 1024 * 1024 * 2;  // 45 MB
  if (ws_size >= full_bytes) {
    rel_kernel<<<2 * 128 * 16, 256, 0, stream>>>(coords, vels, w1, b1, w2, b2,
                                                 relh, 0, 1024);
    attn_mfma<<<1024, 256, 0, stream>>>(qh, kh, vh, relh, 0, 1024, -1, Opart, ml);
  } else {
    for (int c = 0; c < 4; c++) {
      rel_kernel<<<2 * 32 * 16, 256, 0, stream>>>(coords, vels, w1, b1, w2, b2,
                                                  relh, c * 256, 256);
      attn_mfma<<<256, 256, 0, stream>>>(qh, kh, vh, relh, c * 256, 256, c,
                                         Opart, ml);
    }
  }
  combine_kernel<<<256, 256, 0, stream>>>(Opart, ml, attn);
  gemm_kernel<<<dim3(4, 32), 256, 0, stream>>>(attn, w_o, b_o, out, 2048, 256, 256);
}

// Round 8
// 163.648 us; speedup vs baseline: 4.1031x; 1.0071x over previous
//
#include <hip/hip_runtime.h>
#include <hip/hip_bf16.h>
#include <hip/hip_fp16.h>
#include <math.h>
#include <string.h>

typedef _Float16 half8 __attribute__((ext_vector_type(8)));
typedef _Float16 half4 __attribute__((ext_vector_type(4)));
typedef float floatx4 __attribute__((ext_vector_type(4)));

#if defined(__has_builtin) && __has_builtin(__builtin_amdgcn_mfma_f32_16x16x16f16)
#define MFMA_PV(a, b, c) __builtin_amdgcn_mfma_f32_16x16x16f16((a), (b), (c), 0, 0, 0)
#else
__device__ __forceinline__ floatx4 mfma_pv_asm(half4 a, half4 b, floatx4 c) {
  floatx4 d;
  asm volatile("v_mfma_f32_16x16x16_f16 %0, %1, %2, %3"
               : "=v"(d) : "v"(a), "v"(b), "v"(c));
  return d;
}
#define MFMA_PV(a, b, c) mfma_pv_asm((a), (b), (c))
#endif

// ---------------------------------------------------------------------------
// LayerNorm: one block per row (256 elems), block=256
// ---------------------------------------------------------------------------
__global__ __launch_bounds__(256) void ln_kernel(const float* __restrict__ x,
                                                 const float* __restrict__ g,
                                                 const float* __restrict__ bv,
                                                 float* __restrict__ h) {
  int row = blockIdx.x, t = threadIdx.x;
  float v = x[(size_t)row * 256 + t];
  float s = v, q = v * v;
#pragma unroll
  for (int o = 32; o > 0; o >>= 1) {
    s += __shfl_xor(s, o);
    q += __shfl_xor(q, o);
  }
  __shared__ float ss[4], qq[4];
  int w = t >> 6, l = t & 63;
  if (l == 0) { ss[w] = s; qq[w] = q; }
  __syncthreads();
  s = ss[0] + ss[1] + ss[2] + ss[3];
  q = qq[0] + qq[1] + qq[2] + qq[3];
  float mu = s * (1.f / 256.f);
  float var = q * (1.f / 256.f) - mu * mu;
  float inv = rsqrtf(var + 1e-5f);
  h[(size_t)row * 256 + t] = (v - mu) * inv * g[t] + bv[t];
}

// ---------------------------------------------------------------------------
// Tiled fp32 GEMM: C[M,N] = A[M,K] @ B[K,N] (+ bias[n]); BM=BN=64, BK=16
// ---------------------------------------------------------------------------
__global__ __launch_bounds__(256) void gemm_kernel(const float* __restrict__ A,
                                                   const float* __restrict__ Bm,
                                                   const float* __restrict__ bias,
                                                   float* __restrict__ C,
                                                   int M, int N, int K) {
  const int BK = 16;
  __shared__ float As[BK][64];
  __shared__ float Bs[BK][64];
  int tx = threadIdx.x & 15, ty = threadIdx.x >> 4;
  int m0 = blockIdx.y * 64, n0 = blockIdx.x * 64;
  float acc[4][4] = {};
  for (int k0 = 0; k0 < K; k0 += BK) {
    {
      int r = threadIdx.x >> 2;
      int c4 = (threadIdx.x & 3) * 4;
      float4 a = *(const float4*)&A[(size_t)(m0 + r) * K + k0 + c4];
      As[c4 + 0][r] = a.x; As[c4 + 1][r] = a.y;
      As[c4 + 2][r] = a.z; As[c4 + 3][r] = a.w;
    }
    {
      int kk = threadIdx.x >> 4;
      int c4 = (threadIdx.x & 15) * 4;
      *(float4*)&Bs[kk][c4] = *(const float4*)&Bm[(size_t)(k0 + kk) * N + n0 + c4];
    }
    __syncthreads();
#pragma unroll
    for (int kk = 0; kk < BK; kk++) {
      float a[4], bb[4];
#pragma unroll
      for (int r = 0; r < 4; r++) a[r] = As[kk][ty * 4 + r];
#pragma unroll
      for (int c = 0; c < 4; c++) bb[c] = Bs[kk][tx * 4 + c];
#pragma unroll
      for (int r = 0; r < 4; r++)
#pragma unroll
        for (int c = 0; c < 4; c++) acc[r][c] = fmaf(a[r], bb[c], acc[r][c]);
    }
    __syncthreads();
  }
#pragma unroll
  for (int r = 0; r < 4; r++) {
    int row = m0 + ty * 4 + r;
#pragma unroll
    for (int c = 0; c < 4; c++) {
      int col = n0 + tx * 4 + c;
      float val = acc[r][c] + (bias ? bias[col] : 0.f);
      C[(size_t)row * N + col] = val;
    }
  }
}

// ---------------------------------------------------------------------------
// RoPE + split qkv (2048 x 768) -> q,k,v FP16 in (B,H,N,D) layout
// ---------------------------------------------------------------------------
__global__ __launch_bounds__(256) void rope_split(const float* __restrict__ qkv,
                                                  __half* __restrict__ qo,
                                                  __half* __restrict__ ko,
                                                  __half* __restrict__ vo) {
  int row = blockIdx.x;           // b*1024 + n
  int b = row >> 10, n = row & 1023;
  int t = threadIdx.x;            // h*32 + d
  int hh = t >> 5, d = t & 31;
  const float* base = qkv + (size_t)row * 768;
  float vv = base[512 + t];
  int f = d & 15;
  float inv_freq = powf(10000.0f, -(float)f / 16.0f);
  float ang = (float)n * inv_freq;
  float sn, cs;
  sincosf(ang, &sn, &cs);
  float q1 = base[hh * 32 + f], q2 = base[hh * 32 + f + 16];
  float k1 = base[256 + hh * 32 + f], k2 = base[256 + hh * 32 + f + 16];
  float qr = (d < 16) ? (q1 * cs - q2 * sn) : (q2 * cs + q1 * sn);
  float kr = (d < 16) ? (k1 * cs - k2 * sn) : (k2 * cs + k1 * sn);
  size_t oidx = ((size_t)(b * 8 + hh) * 1024 + n) * 32 + d;
  qo[oidx] = __float2half_rn(qr);
  ko[oidx] = __float2half_rn(kr);
  vo[oidx] = __float2half_rn(vv);
}

// ---------------------------------------------------------------------------
// Prepack MLP weights as DUPLICATED half2 (u32): wdup[k][16] =
// {w1[0..4][k], b1[k], w2[k][0..7], 0, 0} each as (h,h). One block, 1024 thr.
// Uniform reads of this table in rel_kernel -> s_load -> SGPR operands.
// ---------------------------------------------------------------------------
__global__ __launch_bounds__(1024) void prepack_kernel(
    const float* __restrict__ w1, const float* __restrict__ b1,
    const float* __restrict__ w2, unsigned int* __restrict__ wdup) {
  int t = threadIdx.x;
  int k = t >> 4, f = t & 15;
  float v = 0.f;
  if (f < 5) v = w1[f * 64 + k];
  else if (f == 5) v = b1[k];
  else if (f < 14) v = w2[k * 8 + (f - 6)];
  __half hv = __float2half_rn(v);
  unsigned short u;
  memcpy(&u, &hv, 2);
  wdup[t] = ((unsigned int)u << 16) | u;
}

__device__ __forceinline__ __half2 u2h2(unsigned int u) {
  __half2 r;
  memcpy(&r, &u, 4);
  return r;
}

// ---------------------------------------------------------------------------
// Relational bias MLP -> rel[b][h][jrel][i] (fp16), TRANSPOSED layout.
// Packed fp16 (v_pk_*_f16 guaranteed) over the two i's of each thread.
// Weights come in via uniform u32 loads (SGPR). No LDS, no barriers.
// gelu(z) = 0.5z + 0.5|z| - 0.5|z|*poly(t)*2^(-0.72135*z^2)  (A-S 7.1.26)
// grid = 2 * (jspan/8) * 16 blocks, 256 threads (th=j(8), tl=i-pair).
// ---------------------------------------------------------------------------
__global__ __launch_bounds__(256) void rel_kernel(
    const float* __restrict__ coords, const float* __restrict__ vels,
    const unsigned int* __restrict__ wdup, const float* __restrict__ b2,
    __half* __restrict__ rel, int j_base, int jspan) {
  const int bx = blockIdx.x;
  const int itile = bx & 15;
  const int rest = bx >> 4;
  const int njg = jspan >> 3;
  const int jg = rest % njg;
  const int b = rest / njg;
  const int t = threadIdx.x;
  const int th = t >> 5, tl = t & 31;
  const int j = j_base + jg * 8 + th;
  const int i = itile * 64 + 2 * tl;

  float2 cj = *(const float2*)&coords[(size_t)(b * 1024 + j) * 2];
  float2 vj = *(const float2*)&vels[(size_t)(b * 1024 + j) * 2];
  float4 ci = *(const float4*)&coords[(size_t)(b * 1024 + i) * 2];  // i, i+1
  float4 vi = *(const float4*)&vels[(size_t)(b * 1024 + i) * 2];
  float dx0a = ci.x - cj.x, dx1a = ci.y - cj.y;
  float dx0b = ci.z - cj.x, dx1b = ci.w - cj.y;
  float dista = sqrtf(dx0a * dx0a + dx1a * dx1a);
  float distb = sqrtf(dx0b * dx0b + dx1b * dx1b);
  const __half2 dx0 = __halves2half2(__float2half_rn(dx0a), __float2half_rn(dx0b));
  const __half2 dx1 = __halves2half2(__float2half_rn(dx1a), __float2half_rn(dx1b));
  const __half2 dst = __halves2half2(__float2half_rn(dista), __float2half_rn(distb));
  const __half2 dv0 = __halves2half2(__float2half_rn(vi.x - vj.x),
                                     __float2half_rn(vi.z - vj.x));
  const __half2 dv1 = __halves2half2(__float2half_rn(vi.y - vj.y),
                                     __float2half_rn(vi.w - vj.y));

  const __half2 c707 = __float2half2_rn(0.70710678f);
  const __half2 c327 = __float2half2_rn(0.3275911f);
  const __half2 one  = __float2half2_rn(1.0f);
  const __half2 chal = __float2half2_rn(0.5f);
  const __half2 cNL  = __float2half2_rn(-0.72134752f);  // -log2(e)/2
  const __half2 cp1  = __float2half2_rn(0.254829592f);
  const __half2 cp2  = __float2half2_rn(-0.284496736f);
  const __half2 cp3  = __float2half2_rn(1.421413741f);
  const __half2 cp4  = __float2half2_rn(-1.453152027f);
  const __half2 cp5  = __float2half2_rn(1.061405429f);

  __half2 accA[8], accB[8];
#pragma unroll
  for (int h = 0; h < 8; h++) { accA[h] = __float2half2_rn(0.f); accB[h] = accA[h]; }

#define REL_BODY(KK, ACC)                                                      \
  {                                                                            \
    const unsigned int* wr = wdup + ((KK) << 4);                               \
    __half2 z = __hfma2(dx0, u2h2(wr[0]),                                      \
                __hfma2(dx1, u2h2(wr[1]),                                      \
                __hfma2(dst, u2h2(wr[2]),                                      \
                __hfma2(dv0, u2h2(wr[3]),                                      \
                __hfma2(dv1, u2h2(wr[4]), u2h2(wr[5]))))));                    \
    __half2 az = __habs2(z);                                                   \
    __half2 a  = __hmul2(az, c707);                                            \
    __half2 tt = h2rcp(__hfma2(a, c327, one));                                 \
    __half2 poly = __hmul2(tt,                                                 \
        __hfma2(tt, __hfma2(tt, __hfma2(tt, __hfma2(tt, cp5, cp4), cp3), cp2), \
                cp1));                                                         \
    __half2 e = h2exp2(__hmul2(__hmul2(az, az), cNL));                         \
    __half2 haz = __hmul2(az, chal);                                           \
    __half2 g = __hsub2(__hfma2(z, chal, haz), __hmul2(haz, __hmul2(poly, e)));\
    ACC[0] = __hfma2(g, u2h2(wr[6]), ACC[0]);                                  \
    ACC[1] = __hfma2(g, u2h2(wr[7]), ACC[1]);                                  \
    ACC[2] = __hfma2(g, u2h2(wr[8]), ACC[2]);                                  \
    ACC[3] = __hfma2(g, u2h2(wr[9]), ACC[3]);                                  \
    ACC[4] = __hfma2(g, u2h2(wr[10]), ACC[4]);                                 \
    ACC[5] = __hfma2(g, u2h2(wr[11]), ACC[5]);                                 \
    ACC[6] = __hfma2(g, u2h2(wr[12]), ACC[6]);                                 \
    ACC[7] = __hfma2(g, u2h2(wr[13]), ACC[7]);                                 \
  }

  for (int kk = 0; kk < 64; kk += 2) {
    REL_BODY(kk, accA)
    REL_BODY(kk + 1, accB)
  }
#undef REL_BODY

#pragma unroll
  for (int h = 0; h < 8; h++) {
    float bb = b2[h];
    float sx = __low2float(accA[h]) + __low2float(accB[h]) + bb;
    float sy = __high2float(accA[h]) + __high2float(accB[h]) + bb;
    __half2 hv = __halves2half2(__float2half_rn(sx), __float2half_rn(sy));
    *(__half2*)&rel[((size_t)(b * 8 + h) * jspan + (j - j_base)) * 1024 + i] = hv;
  }
}

// ---------------------------------------------------------------------------
// MFMA flash attention. One wave = (b, h, i-tile of 16, j-quarter of 256).
// S^T = mfma_16x16x32_f16(K-frag, Q-frag): lane l&15 = i -> softmax reduction
// is 3 in-lane fmax + 2 shuffles. P stays in-lane as the A-frag of
// PV = mfma_16x16x16_f16(P, V). No LDS, no barriers.
// js_force < 0: full (4 j-quarters, grid 1024); else chunked (grid 256).
// ---------------------------------------------------------------------------
__global__ __launch_bounds__(256) void attn_mfma(
    const __half* __restrict__ qh, const __half* __restrict__ kh,
    const __half* __restrict__ vh, const __half* __restrict__ rel,
    int j_base, int jspan, int js_force,
    float* __restrict__ Opart, float* __restrict__ ml) {
  const int task = blockIdx.x * 4 + (threadIdx.x >> 6);
  int js, it, h, b;
  if (js_force >= 0) {
    js = js_force; it = task & 63; h = (task >> 6) & 7; b = task >> 9;
  } else {
    js = task & 3; it = (task >> 2) & 63; h = (task >> 8) & 7; b = task >> 11;
  }
  const int lane = threadIdx.x & 63;
  const int lg = lane >> 4;   // k-block / j-subrow group
  const int li = lane & 15;   // i (softmax) / col index
  const int i0 = it * 16;
  const size_t bh = (size_t)(b * 8 + h) * 1024;
  const float scale = 0.17677669529663687f;  // 1/sqrt(32)

  // Q fragment (B operand): Q[i0+li][8*lg .. +7]
  const half8 qf = *(const half8*)((const _Float16*)qh + (bh + i0 + li) * 32 + 8 * lg);

  floatx4 accLo = {0.f, 0.f, 0.f, 0.f};
  floatx4 accHi = {0.f, 0.f, 0.f, 0.f};
  float m_run = -3.0e38f, l_run = 0.f;

  for (int jt = js * 256; jt < js * 256 + 256; jt += 16) {
    // K fragment (A operand): K[jt+li][8*lg .. +7]
    half8 kf = *(const half8*)((const _Float16*)kh + (bh + jt + li) * 32 + 8 * lg);
    floatx4 zero = {0.f, 0.f, 0.f, 0.f};
    floatx4 st = __builtin_amdgcn_mfma_f32_16x16x32_f16(kf, qf, zero, 0, 0, 0);
    // st[r] = S[i = i0+li][j = jt + 4*lg + r]
    const __half* rrow = rel + ((size_t)(b * 8 + h) * jspan + (jt - j_base + 4 * lg)) * 1024 + i0 + li;
    float s0 = fmaf(st[0], scale, __half2float(rrow[0]));
    float s1 = fmaf(st[1], scale, __half2float(rrow[1024]));
    float s2 = fmaf(st[2], scale, __half2float(rrow[2048]));
    float s3 = fmaf(st[3], scale, __half2float(rrow[3072]));
    // online softmax over the 16 j of this tile (per i = li)
    float tm = fmaxf(fmaxf(s0, s1), fmaxf(s2, s3));
    tm = fmaxf(tm, __shfl_xor(tm, 16));
    tm = fmaxf(tm, __shfl_xor(tm, 32));
    float nm = fmaxf(m_run, tm);
    float fc = __expf(m_run - nm);
    float p0 = __expf(s0 - nm);
    float p1 = __expf(s1 - nm);
    float p2 = __expf(s2 - nm);
    float p3 = __expf(s3 - nm);
    float ts = (p0 + p1) + (p2 + p3);
    ts += __shfl_xor(ts, 16);
    ts += __shfl_xor(ts, 32);
    l_run = l_run * fc + ts;
    m_run = nm;
    // rescale O: acc rows are i = i0 + 4*lg + r -> fetch fc from lane 4*lg+r
    float fT0 = __shfl(fc, 4 * lg + 0);
    float fT1 = __shfl(fc, 4 * lg + 1);
    float fT2 = __shfl(fc, 4 * lg + 2);
    float fT3 = __shfl(fc, 4 * lg + 3);
    accLo[0] *= fT0; accHi[0] *= fT0;
    accLo[1] *= fT1; accHi[1] *= fT1;
    accLo[2] *= fT2; accHi[2] *= fT2;
    accLo[3] *= fT3; accHi[3] *= fT3;
    // P fragment (A operand of PV): A[m=li][k=4*lg+q] = p_q  -- already in-lane
    half4 pf;
    pf[0] = (_Float16)p0; pf[1] = (_Float16)p1;
    pf[2] = (_Float16)p2; pf[3] = (_Float16)p3;
    // V fragments (B operand): V[jt + 4*lg + q][d], d = li / li+16
    const _Float16* vb = (const _Float16*)vh + (bh + jt + 4 * lg) * 32 + li;
    half4 vf0, vf1;
    vf0[0] = vb[0];  vf0[1] = vb[32]; vf0[2] = vb[64]; vf0[3] = vb[96];
    vf1[0] = vb[16]; vf1[1] = vb[48]; vf1[2] = vb[80]; vf1[3] = vb[112];
    accLo = MFMA_PV(pf, vf0, accLo);
    accHi = MFMA_PV(pf, vf1, accHi);
  }
  // write partials: O rows i = i0 + 4*lg + r, cols h*32 + li (+16)
  size_t orow = (size_t)(b * 4 + js) * 1024 + i0 + 4 * lg;
#pragma unroll
  for (int r = 0; r < 4; r++) {
    float* op = Opart + (orow + r) * 256 + h * 32 + li;
    op[0] = accLo[r];
    op[16] = accHi[r];
  }
  if (lane < 16) {
    ((float2*)ml)[((size_t)(b * 4 + js) * 1024 + i0 + lane) * 8 + h] =
        make_float2(m_run, l_run);
  }
}

// ---------------------------------------------------------------------------
// Combine j-split partials: grid = 256 blocks (b, i-group of 8), 256 threads.
// ---------------------------------------------------------------------------
__global__ __launch_bounds__(256) void combine_kernel(
    const float* __restrict__ Opart, const float* __restrict__ ml,
    float* __restrict__ attn) {
  int b = blockIdx.x >> 7, ig = blockIdx.x & 127;
  int i0 = ig * 8;
  int t = threadIdx.x, hh = t >> 5;
#pragma unroll
  for (int i = 0; i < 8; i++) {
    float2 mls[4];
    float M = -1e30f;
#pragma unroll
    for (int js = 0; js < 4; js++) {
      mls[js] = ((const float2*)ml)[(((size_t)(b * 4 + js) * 1024) + i0 + i) * 8 + hh];
      M = fmaxf(M, mls[js].x);
    }
    float L = 0.f, Ov = 0.f;
#pragma unroll
    for (int js = 0; js < 4; js++) {
      float w = __expf(mls[js].x - M);
      L += mls[js].y * w;
      Ov += Opart[(((size_t)(b * 4 + js) * 1024) + i0 + i) * 256 + t] * w;
    }
    attn[((size_t)b * 1024 + i0 + i) * 256 + t] = Ov / L;
  }
}

// ---------------------------------------------------------------------------
extern "C" void kernel_launch(void* const* d_in, const int* in_sizes, int n_in,
                              void* d_out, int out_size, void* d_ws, size_t ws_size,
                              hipStream_t stream) {
  const float* x      = (const float*)d_in[0];
  const float* coords = (const float*)d_in[1];
  const float* vels   = (const float*)d_in[2];
  const float* ln_g   = (const float*)d_in[3];
  const float* ln_b   = (const float*)d_in[4];
  const float* w_qkv  = (const float*)d_in[5];
  const float* w_o    = (const float*)d_in[6];
  const float* b_o    = (const float*)d_in[7];
  const float* w1     = (const float*)d_in[8];
  const float* b1     = (const float*)d_in[9];
  const float* w2     = (const float*)d_in[10];
  const float* b2     = (const float*)d_in[11];
  float* out = (float*)d_out;

  // ws layout (bytes):
  //  [0, 2MB)    h_ln (fp32, dead after qkv gemm)      \ reused as Opart
  //  [2MB, 8MB)  qkv  (fp32, dead after rope)          /  [0, 8MB) fp32
  //  [8MB, 9MB)  qh fp16   [9,10) kh   [10,11) vh
  //  [11MB,13MB) attn fp32
  //  [13631488, +4KB) wdup (packed MLP weights)
  //  [13635584, ...) rel fp16: full 32MB; chunk 8MB
  float* ws    = (float*)d_ws;
  float* h_ln  = ws;
  float* qkv   = ws + 524288;
  float* Opart = ws;
  __half* qh   = (__half*)((char*)d_ws + 8388608);
  __half* kh   = qh + 524288;
  __half* vh   = kh + 524288;
  float* attn  = (float*)((char*)d_ws + 11534336);
  unsigned int* wdup = (unsigned int*)((char*)d_ws + 13631488);
  __half* relh = (__half*)((char*)d_ws + 13635584);
  float* ml    = (float*)d_out;  // scratch; final gemm fully rewrites d_out

  ln_kernel<<<2048, 256, 0, stream>>>(x, ln_g, ln_b, h_ln);
  gemm_kernel<<<dim3(12, 32), 256, 0, stream>>>(h_ln, w_qkv, nullptr, qkv, 2048, 768, 256);
  rope_split<<<2048, 256, 0, stream>>>(qkv, qh, kh, vh);
  prepack_kernel<<<1, 1024, 0, stream>>>(w1, b1, w2, wdup);

  const size_t full_bytes = 13635584ull + 2ull * 8 * 1024 * 1024 * 2;  // ~45 MB
  if (ws_size >= full_bytes) {
    rel_kernel<<<2 * 128 * 16, 256, 0, stream>>>(coords, vels, wdup, b2,
                                                 relh, 0, 1024);
    attn_mfma<<<1024, 256, 0, stream>>>(qh, kh, vh, relh, 0, 1024, -1, Opart, ml);
  } else {
    for (int c = 0; c < 4; c++) {
      rel_kernel<<<2 * 32 * 16, 256, 0, stream>>>(coords, vels, wdup, b2,
                                                  relh, c * 256, 256);
      attn_mfma<<<256, 256, 0, stream>>>(qh, kh, vh, relh, c * 256, 256, c,
                                         Opart, ml);
    }
  }
  combine_kernel<<<256, 256, 0, stream>>>(Opart, ml, attn);
  gemm_kernel<<<dim3(4, 32), 256, 0, stream>>>(attn, w_o, b_o, out, 2048, 256, 256);
}

// Round 9
// 135.077 us; speedup vs baseline: 4.9709x; 1.2115x over previous
//
#include <hip/hip_runtime.h>
#include <hip/hip_bf16.h>
#include <hip/hip_fp16.h>
#include <math.h>
#include <string.h>

typedef _Float16 half8 __attribute__((ext_vector_type(8)));
typedef _Float16 half4 __attribute__((ext_vector_type(4)));
typedef float floatx4 __attribute__((ext_vector_type(4)));
typedef float floatx16 __attribute__((ext_vector_type(16)));

#if defined(__has_builtin) && __has_builtin(__builtin_amdgcn_mfma_f32_16x16x16f16)
#define MFMA_PV(a, b, c) __builtin_amdgcn_mfma_f32_16x16x16f16((a), (b), (c), 0, 0, 0)
#else
__device__ __forceinline__ floatx4 mfma_pv_asm(half4 a, half4 b, floatx4 c) {
  floatx4 d;
  asm volatile("v_mfma_f32_16x16x16_f16 %0, %1, %2, %3"
               : "=v"(d) : "v"(a), "v"(b), "v"(c));
  return d;
}
#define MFMA_PV(a, b, c) mfma_pv_asm((a), (b), (c))
#endif

__device__ __forceinline__ floatx16 MFMA_S1(half4 a, half4 b, floatx16 c) {
#if defined(__has_builtin) && __has_builtin(__builtin_amdgcn_mfma_f32_32x32x8f16)
  return __builtin_amdgcn_mfma_f32_32x32x8f16(a, b, c, 0, 0, 0);
#else
  floatx16 d;
  asm volatile("v_mfma_f32_32x32x8_f16 %0, %1, %2, %3"
               : "=v"(d) : "v"(a), "v"(b), "v"(c));
  return d;
#endif
}

__device__ __forceinline__ floatx16 MFMA_S2(half8 a, half8 b, floatx16 c) {
#if defined(__has_builtin) && __has_builtin(__builtin_amdgcn_mfma_f32_32x32x16_f16)
  return __builtin_amdgcn_mfma_f32_32x32x16_f16(a, b, c, 0, 0, 0);
#else
  floatx16 d;
  asm volatile("v_mfma_f32_32x32x16_f16 %0, %1, %2, %3"
               : "=v"(d) : "v"(a), "v"(b), "v"(c));
  return d;
#endif
}

// ---------------------------------------------------------------------------
// LayerNorm -> f16 output
// ---------------------------------------------------------------------------
__global__ __launch_bounds__(256) void ln_kernel(const float* __restrict__ x,
                                                 const float* __restrict__ g,
                                                 const float* __restrict__ bv,
                                                 __half* __restrict__ h16) {
  int row = blockIdx.x, t = threadIdx.x;
  float v = x[(size_t)row * 256 + t];
  float s = v, q = v * v;
#pragma unroll
  for (int o = 32; o > 0; o >>= 1) {
    s += __shfl_xor(s, o);
    q += __shfl_xor(q, o);
  }
  __shared__ float ss[4], qq[4];
  int w = t >> 6, l = t & 63;
  if (l == 0) { ss[w] = s; qq[w] = q; }
  __syncthreads();
  s = ss[0] + ss[1] + ss[2] + ss[3];
  q = qq[0] + qq[1] + qq[2] + qq[3];
  float mu = s * (1.f / 256.f);
  float var = q * (1.f / 256.f) - mu * mu;
  float inv = rsqrtf(var + 1e-5f);
  h16[(size_t)row * 256 + t] = __float2half_rn((v - mu) * inv * g[t] + bv[t]);
}

// ---------------------------------------------------------------------------
// Setup: transpose weights to f16, build exact-GELU lerp table + MFMA frags.
// grid = 1026 x 256.
// ---------------------------------------------------------------------------
__device__ __forceinline__ float gelu_exact(float z) {
  return 0.5f * z * (1.0f + erff(z * 0.70710678118654752f));
}
__device__ __forceinline__ unsigned int packh2(float a, float b) {
  __half2 h = __halves2half2(__float2half_rn(a), __float2half_rn(b));
  unsigned int u;
  memcpy(&u, &h, 4);
  return u;
}

__global__ __launch_bounds__(256) void setup_kernel(
    const float* __restrict__ w_qkv, const float* __restrict__ w_o,
    const float* __restrict__ w1, const float* __restrict__ b1,
    const float* __restrict__ w2,
    __half* __restrict__ wqT, __half* __restrict__ woT,
    float2* __restrict__ gtabg, uint2* __restrict__ A1g,
    uint4* __restrict__ A2g) {
  int bx = blockIdx.x, t = threadIdx.x;
  if (bx < 768) {
    wqT[(size_t)bx * 256 + t] = __float2half_rn(w_qkv[(size_t)t * 768 + bx]);
  } else if (bx < 1024) {
    int n = bx - 768;
    woT[(size_t)n * 256 + t] = __float2half_rn(w_o[(size_t)t * 256 + n]);
  } else if (bx == 1024) {
#pragma unroll
    for (int s = 0; s < 8; s++) {
      int e = t * 8 + s;
      float z = -16.f + (float)e * (1.f / 64.f);
      float g0 = gelu_exact(z);
      float g1 = gelu_exact(z + (1.f / 64.f));
      gtabg[e] = make_float2(g0, g1 - g0);
    }
  } else {
    // A1 frags: [2 hidden-blocks][64 lanes] -> 4 halves (K=8 stage-1 weights)
    if (t < 128) {
      int hb = t >> 6, l = t & 63;
      int hid = hb * 32 + (l & 31);
      float v[4];
#pragma unroll
      for (int e = 0; e < 4; e++) {
        int k = (l >> 5) * 4 + e;
        v[e] = (k < 5) ? w1[k * 64 + hid] : ((k == 5) ? b1[hid] : 0.f);
      }
      A1g[t] = make_uint2(packh2(v[0], v[1]), packh2(v[2], v[3]));
    }
    // A2 frags: [4 K-chunks][64 lanes] -> 8 halves (stage-2 w2^T, M rows 0-7)
    {
      int c = t >> 6, l = t & 63;
      int row = l & 31;
      float v[8];
#pragma unroll
      for (int e = 0; e < 8; e++) {
        int hid = c * 16 + (l >> 5) * 8 + e;
        v[e] = (row < 8) ? w2[hid * 8 + row] : 0.f;
      }
      A2g[t] = make_uint4(packh2(v[0], v[1]), packh2(v[2], v[3]),
                          packh2(v[4], v[5]), packh2(v[6], v[7]));
    }
  }
}

// ---------------------------------------------------------------------------
// f16 MFMA GEMM: C[M,N] f32 = A16[M,K] @ BT16[N,K]^T (+ bias). Wave = 16x16
// tile, K in chunks of 32. grid = (M/16 * N/16)/4 blocks x 256.
// ---------------------------------------------------------------------------
__global__ __launch_bounds__(256) void gemm16(
    const __half* __restrict__ A16, const __half* __restrict__ BT16,
    const float* __restrict__ bias, float* __restrict__ C,
    int ntn, int N, int K) {
  int wave = blockIdx.x * 4 + (threadIdx.x >> 6);
  int mt = wave / ntn, nt = wave - mt * ntn;
  int l = threadIdx.x & 63;
  int lg = l >> 4, li = l & 15;
  int m0 = mt * 16, n0 = nt * 16;
  floatx4 acc = {0.f, 0.f, 0.f, 0.f};
  for (int k0 = 0; k0 < K; k0 += 32) {
    half8 af = *(const half8*)((const _Float16*)A16 + (size_t)(m0 + li) * K + k0 + 8 * lg);
    half8 bf = *(const half8*)((const _Float16*)BT16 + (size_t)(n0 + li) * K + k0 + 8 * lg);
    acc = __builtin_amdgcn_mfma_f32_16x16x32_f16(af, bf, acc, 0, 0, 0);
  }
  float bb = bias ? bias[n0 + li] : 0.f;
#pragma unroll
  for (int r = 0; r < 4; r++) {
    C[(size_t)(m0 + 4 * lg + r) * N + n0 + li] = acc[r] + bb;
  }
}

// ---------------------------------------------------------------------------
// RoPE + split qkv (2048 x 768 f32) -> q,k,v FP16 in (B,H,N,D); fast trig
// ---------------------------------------------------------------------------
__global__ __launch_bounds__(256) void rope_split(const float* __restrict__ qkv,
                                                  __half* __restrict__ qo,
                                                  __half* __restrict__ ko,
                                                  __half* __restrict__ vo) {
  int row = blockIdx.x;
  int b = row >> 10, n = row & 1023;
  int t = threadIdx.x;
  int hh = t >> 5, d = t & 31;
  const float* base = qkv + (size_t)row * 768;
  float vv = base[512 + t];
  int f = d & 15;
  float inv_freq = exp2f((float)f * -0.8304820237218407f);  // 10000^(-f/16)
  float ang = (float)n * inv_freq;
  float sn, cs;
  __sincosf(ang, &sn, &cs);
  float q1 = base[hh * 32 + f], q2 = base[hh * 32 + f + 16];
  float k1 = base[256 + hh * 32 + f], k2 = base[256 + hh * 32 + f + 16];
  float qr = (d < 16) ? (q1 * cs - q2 * sn) : (q2 * cs + q1 * sn);
  float kr = (d < 16) ? (k1 * cs - k2 * sn) : (k2 * cs + k1 * sn);
  size_t oidx = ((size_t)(b * 8 + hh) * 1024 + n) * 32 + d;
  qo[oidx] = __float2half_rn(qr);
  ko[oidx] = __float2half_rn(kr);
  vo[oidx] = __float2half_rn(vv);
}

// ---------------------------------------------------------------------------
// Table GELU: exact erf-GELU lerp table, step 1/64 on [-16,16), linear tail.
// ---------------------------------------------------------------------------
__device__ __forceinline__ float gelu_tab(float z, const float2* gt) {
  float zc = fminf(fmaxf(z, -16.f), 15.984375f);
  float tf = fmaf(zc, 64.f, 1024.f);
  float fl = floorf(tf);
  float fr = tf - fl;
  float2 e = gt[(int)fl];
  float g = fmaf(fr, e.y, e.x);
  return g + fmaxf(z - 15.984375f, 0.f);
}

// ---------------------------------------------------------------------------
// Relational bias via double MFMA + table GELU -> rel[b][h][jrel][i] (fp16).
// Block = (b, j): 4 waves x 8 i-tiles of 32. Per tile:
//   z[64][32] = 2x mfma_32x32x8(A1=w1^T, feats)      (f32 accum)
//   g = table-gelu(z)  (scalar f32, LDS lerp)
//   rel8[8][32] = 4x mfma_32x32x16(A2=w2^T, g-frag)  accumulated
// Cross-half g exchange: shfl_xor(32) + static selects (D-layout derived).
// ---------------------------------------------------------------------------
__global__ __launch_bounds__(256) void rel_kernel(
    const float* __restrict__ coords, const float* __restrict__ vels,
    const float2* __restrict__ gtabg, const uint2* __restrict__ A1g,
    const uint4* __restrict__ A2g, const float* __restrict__ b2,
    __half* __restrict__ rel, int j_base, int jspan) {
  __shared__ float2 gtab[2048];
  const int t = threadIdx.x;
  for (int e = t; e < 2048; e += 256) gtab[e] = gtabg[e];
  const int b = blockIdx.x / jspan;
  const int j = j_base + (blockIdx.x - b * jspan);
  const int wv = t >> 6;
  const int l = t & 63;
  const int li = l & 31, lh = l >> 5;

  uint2 a1u0 = A1g[l], a1u1 = A1g[64 + l];
  uint4 a2u0 = A2g[l], a2u1 = A2g[64 + l], a2u2 = A2g[128 + l], a2u3 = A2g[192 + l];
  float2 cj = *(const float2*)&coords[(size_t)(b * 1024 + j) * 2];
  float2 vj = *(const float2*)&vels[(size_t)(b * 1024 + j) * 2];
  float b2v0 = b2[4 * lh + 0], b2v1 = b2[4 * lh + 1];
  float b2v2 = b2[4 * lh + 2], b2v3 = b2[4 * lh + 3];
  const size_t hstride = (size_t)jspan * 1024;
  __syncthreads();

  for (int itg = 0; itg < 8; itg++) {
    const int i0 = (wv * 8 + itg) * 32;
    const int i = i0 + li;
    float2 ci = *(const float2*)&coords[(size_t)(b * 1024 + i) * 2];
    float2 vi = *(const float2*)&vels[(size_t)(b * 1024 + i) * 2];
    float dx0 = ci.x - cj.x, dx1 = ci.y - cj.y;
    float dv0 = vi.x - vj.x, dv1 = vi.y - vj.y;
    float dist = sqrtf(dx0 * dx0 + dx1 * dx1);
    // feats frag: pair=li, k-slots (lh*4 + 0..3): {dx0,dx1,dist,dv0 | dv1,1,0,0}
    half4 bf;
    bf[0] = lh ? (_Float16)dv1 : (_Float16)dx0;
    bf[1] = lh ? (_Float16)1.0f : (_Float16)dx1;
    bf[2] = lh ? (_Float16)0.0f : (_Float16)dist;
    bf[3] = lh ? (_Float16)0.0f : (_Float16)dv0;

    floatx16 zinit = {0.f};
    floatx16 acc = {0.f};

    // ---- hidden block 0 (hidden 0..31) ----
    {
      floatx16 z0 = MFMA_S1(*(half4*)&a1u0, bf, zinit);
      unsigned int u[8], p[8];
#pragma unroll
      for (int q = 0; q < 4; q++) {
        float g0 = gelu_tab(z0[4 * q + 0], gtab);
        float g1 = gelu_tab(z0[4 * q + 1], gtab);
        float g2 = gelu_tab(z0[4 * q + 2], gtab);
        float g3 = gelu_tab(z0[4 * q + 3], gtab);
        u[2 * q] = packh2(g0, g1);
        u[2 * q + 1] = packh2(g2, g3);
      }
#pragma unroll
      for (int e = 0; e < 8; e++) p[e] = __shfl_xor(u[e], 32);
#pragma unroll
      for (int cc = 0; cc < 2; cc++) {
        const int q = 2 * cc, qq = q + 1;
        uint4 bw;
        bw.x = lh ? p[2 * qq] : u[2 * q];
        bw.y = lh ? p[2 * qq + 1] : u[2 * q + 1];
        bw.z = lh ? u[2 * qq] : p[2 * q];
        bw.w = lh ? u[2 * qq + 1] : p[2 * q + 1];
        acc = MFMA_S2(cc == 0 ? *(half8*)&a2u0 : *(half8*)&a2u1,
                      *(half8*)&bw, acc);
      }
    }
    // ---- hidden block 1 (hidden 32..63) ----
    {
      floatx16 z1 = MFMA_S1(*(half4*)&a1u1, bf, zinit);
      unsigned int u[8], p[8];
#pragma unroll
      for (int q = 0; q < 4; q++) {
        float g0 = gelu_tab(z1[4 * q + 0], gtab);
        float g1 = gelu_tab(z1[4 * q + 1], gtab);
        float g2 = gelu_tab(z1[4 * q + 2], gtab);
        float g3 = gelu_tab(z1[4 * q + 3], gtab);
        u[2 * q] = packh2(g0, g1);
        u[2 * q + 1] = packh2(g2, g3);
      }
#pragma unroll
      for (int e = 0; e < 8; e++) p[e] = __shfl_xor(u[e], 32);
#pragma unroll
      for (int cc = 0; cc < 2; cc++) {
        const int q = 2 * cc, qq = q + 1;
        uint4 bw;
        bw.x = lh ? p[2 * qq] : u[2 * q];
        bw.y = lh ? p[2 * qq + 1] : u[2 * q + 1];
        bw.z = lh ? u[2 * qq] : p[2 * q];
        bw.w = lh ? u[2 * qq + 1] : p[2 * q + 1];
        acc = MFMA_S2(cc == 0 ? *(half8*)&a2u2 : *(half8*)&a2u3,
                      *(half8*)&bw, acc);
      }
    }
    // epilogue: heads 4*lh + 0..3 live in acc[0..3]
    size_t base = ((size_t)(b * 8) * jspan + (size_t)(j - j_base)) * 1024 + i;
    rel[base + (size_t)(4 * lh + 0) * hstride] = __float2half_rn(acc[0] + b2v0);
    rel[base + (size_t)(4 * lh + 1) * hstride] = __float2half_rn(acc[1] + b2v1);
    rel[base + (size_t)(4 * lh + 2) * hstride] = __float2half_rn(acc[2] + b2v2);
    rel[base + (size_t)(4 * lh + 3) * hstride] = __float2half_rn(acc[3] + b2v3);
  }
}

// ---------------------------------------------------------------------------
// MFMA flash attention (unchanged from R6/R7, verified).
// ---------------------------------------------------------------------------
__global__ __launch_bounds__(256) void attn_mfma(
    const __half* __restrict__ qh, const __half* __restrict__ kh,
    const __half* __restrict__ vh, const __half* __restrict__ rel,
    int j_base, int jspan, int js_force,
    float* __restrict__ Opart, float* __restrict__ ml) {
  const int task = blockIdx.x * 4 + (threadIdx.x >> 6);
  int js, it, h, b;
  if (js_force >= 0) {
    js = js_force; it = task & 63; h = (task >> 6) & 7; b = task >> 9;
  } else {
    js = task & 3; it = (task >> 2) & 63; h = (task >> 8) & 7; b = task >> 11;
  }
  const int lane = threadIdx.x & 63;
  const int lg = lane >> 4;
  const int li = lane & 15;
  const int i0 = it * 16;
  const size_t bh = (size_t)(b * 8 + h) * 1024;
  const float scale = 0.17677669529663687f;

  const half8 qf = *(const half8*)((const _Float16*)qh + (bh + i0 + li) * 32 + 8 * lg);

  floatx4 accLo = {0.f, 0.f, 0.f, 0.f};
  floatx4 accHi = {0.f, 0.f, 0.f, 0.f};
  float m_run = -3.0e38f, l_run = 0.f;

  for (int jt = js * 256; jt < js * 256 + 256; jt += 16) {
    half8 kf = *(const half8*)((const _Float16*)kh + (bh + jt + li) * 32 + 8 * lg);
    floatx4 zero = {0.f, 0.f, 0.f, 0.f};
    floatx4 st = __builtin_amdgcn_mfma_f32_16x16x32_f16(kf, qf, zero, 0, 0, 0);
    const __half* rrow = rel + ((size_t)(b * 8 + h) * jspan + (jt - j_base + 4 * lg)) * 1024 + i0 + li;
    float s0 = fmaf(st[0], scale, __half2float(rrow[0]));
    float s1 = fmaf(st[1], scale, __half2float(rrow[1024]));
    float s2 = fmaf(st[2], scale, __half2float(rrow[2048]));
    float s3 = fmaf(st[3], scale, __half2float(rrow[3072]));
    float tm = fmaxf(fmaxf(s0, s1), fmaxf(s2, s3));
    tm = fmaxf(tm, __shfl_xor(tm, 16));
    tm = fmaxf(tm, __shfl_xor(tm, 32));
    float nm = fmaxf(m_run, tm);
    float fc = __expf(m_run - nm);
    float p0 = __expf(s0 - nm);
    float p1 = __expf(s1 - nm);
    float p2 = __expf(s2 - nm);
    float p3 = __expf(s3 - nm);
    float ts = (p0 + p1) + (p2 + p3);
    ts += __shfl_xor(ts, 16);
    ts += __shfl_xor(ts, 32);
    l_run = l_run * fc + ts;
    m_run = nm;
    float fT0 = __shfl(fc, 4 * lg + 0);
    float fT1 = __shfl(fc, 4 * lg + 1);
    float fT2 = __shfl(fc, 4 * lg + 2);
    float fT3 = __shfl(fc, 4 * lg + 3);
    accLo[0] *= fT0; accHi[0] *= fT0;
    accLo[1] *= fT1; accHi[1] *= fT1;
    accLo[2] *= fT2; accHi[2] *= fT2;
    accLo[3] *= fT3; accHi[3] *= fT3;
    half4 pf;
    pf[0] = (_Float16)p0; pf[1] = (_Float16)p1;
    pf[2] = (_Float16)p2; pf[3] = (_Float16)p3;
    const _Float16* vb = (const _Float16*)vh + (bh + jt + 4 * lg) * 32 + li;
    half4 vf0, vf1;
    vf0[0] = vb[0];  vf0[1] = vb[32]; vf0[2] = vb[64]; vf0[3] = vb[96];
    vf1[0] = vb[16]; vf1[1] = vb[48]; vf1[2] = vb[80]; vf1[3] = vb[112];
    accLo = MFMA_PV(pf, vf0, accLo);
    accHi = MFMA_PV(pf, vf1, accHi);
  }
  size_t orow = (size_t)(b * 4 + js) * 1024 + i0 + 4 * lg;
#pragma unroll
  for (int r = 0; r < 4; r++) {
    float* op = Opart + (orow + r) * 256 + h * 32 + li;
    op[0] = accLo[r];
    op[16] = accHi[r];
  }
  if (lane < 16) {
    ((float2*)ml)[((size_t)(b * 4 + js) * 1024 + i0 + lane) * 8 + h] =
        make_float2(m_run, l_run);
  }
}

// ---------------------------------------------------------------------------
// Combine j-split partials -> attn16 (f16, feeds the out-proj MFMA GEMM)
// ---------------------------------------------------------------------------
__global__ __launch_bounds__(256) void combine_kernel(
    const float* __restrict__ Opart, const float* __restrict__ ml,
    __half* __restrict__ attn16) {
  int b = blockIdx.x >> 7, ig = blockIdx.x & 127;
  int i0 = ig * 8;
  int t = threadIdx.x, hh = t >> 5;
#pragma unroll
  for (int i = 0; i < 8; i++) {
    float2 mls[4];
    float M = -1e30f;
#pragma unroll
    for (int js = 0; js < 4; js++) {
      mls[js] = ((const float2*)ml)[(((size_t)(b * 4 + js) * 1024) + i0 + i) * 8 + hh];
      M = fmaxf(M, mls[js].x);
    }
    float L = 0.f, Ov = 0.f;
#pragma unroll
    for (int js = 0; js < 4; js++) {
      float w = __expf(mls[js].x - M);
      L += mls[js].y * w;
      Ov += Opart[(((size_t)(b * 4 + js) * 1024) + i0 + i) * 256 + t] * w;
    }
    attn16[((size_t)b * 1024 + i0 + i) * 256 + t] = __float2half_rn(Ov / L);
  }
}

// ---------------------------------------------------------------------------
extern "C" void kernel_launch(void* const* d_in, const int* in_sizes, int n_in,
                              void* d_out, int out_size, void* d_ws, size_t ws_size,
                              hipStream_t stream) {
  const float* x      = (const float*)d_in[0];
  const float* coords = (const float*)d_in[1];
  const float* vels   = (const float*)d_in[2];
  const float* ln_g   = (const float*)d_in[3];
  const float* ln_b   = (const float*)d_in[4];
  const float* w_qkv  = (const float*)d_in[5];
  const float* w_o    = (const float*)d_in[6];
  const float* b_o    = (const float*)d_in[7];
  const float* w1     = (const float*)d_in[8];
  const float* b1     = (const float*)d_in[9];
  const float* w2     = (const float*)d_in[10];
  const float* b2     = (const float*)d_in[11];
  float* out = (float*)d_out;

  // ws layout (bytes):
  //  [0, 8Mi)        Opart f32 (written by attn, after qkv is dead)
  //  [2Mi, 8Mi)      qkv f32 (dead after rope)
  //  [8Mi, +545KB)   wqT f16 | woT f16 | gtab | A1 | A2
  //  [9Mi, 10Mi)     h16 (ln out) -> overwritten by qh after qkv gemm
  //  [10Mi,11Mi) kh  [11Mi,12Mi) vh  [12Mi,13Mi) attn16
  //  [13Mi, 45Mi)    rel f16 full (chunk fallback: 8Mi)
  char* wsb = (char*)d_ws;
  float* Opart = (float*)wsb;
  float* qkv   = (float*)(wsb + 2097152);
  __half* wqT  = (__half*)(wsb + 8388608);
  __half* woT  = (__half*)(wsb + 8781824);
  float2* gtab = (float2*)(wsb + 8912896);
  uint2* A1g   = (uint2*)(wsb + 8929280);
  uint4* A2g   = (uint4*)(wsb + 8930304);
  __half* h16  = (__half*)(wsb + 9437184);
  __half* qh   = (__half*)(wsb + 9437184);
  __half* kh   = (__half*)(wsb + 10485760);
  __half* vh   = (__half*)(wsb + 11534336);
  __half* attn16 = (__half*)(wsb + 12582912);
  __half* relh = (__half*)(wsb + 13631488);
  float* ml    = (float*)d_out;  // scratch; final gemm fully rewrites d_out

  ln_kernel<<<2048, 256, 0, stream>>>(x, ln_g, ln_b, h16);
  setup_kernel<<<1026, 256, 0, stream>>>(w_qkv, w_o, w1, b1, w2,
                                         wqT, woT, gtab, A1g, A2g);
  gemm16<<<1536, 256, 0, stream>>>(h16, wqT, nullptr, qkv, 48, 768, 256);
  rope_split<<<2048, 256, 0, stream>>>(qkv, qh, kh, vh);

  const size_t full_bytes = 13631488ull + 33554432ull;  // 45 MiB
  if (ws_size >= full_bytes) {
    rel_kernel<<<2048, 256, 0, stream>>>(coords, vels, gtab, A1g, A2g, b2,
                                         relh, 0, 1024);
    attn_mfma<<<1024, 256, 0, stream>>>(qh, kh, vh, relh, 0, 1024, -1, Opart, ml);
  } else {
    for (int c = 0; c < 4; c++) {
      rel_kernel<<<512, 256, 0, stream>>>(coords, vels, gtab, A1g, A2g, b2,
                                          relh, c * 256, 256);
      attn_mfma<<<256, 256, 0, stream>>>(qh, kh, vh, relh, c * 256, 256, c,
                                         Opart, ml);
    }
  }
  combine_kernel<<<256, 256, 0, stream>>>(Opart, ml, attn16);
  gemm16<<<512, 256, 0, stream>>>(attn16, woT, b_o, out, 16, 256, 256);
}

// Round 10
// 122.836 us; speedup vs baseline: 5.4663x; 1.0997x over previous
//
#include <hip/hip_runtime.h>
#include <hip/hip_bf16.h>
#include <hip/hip_fp16.h>
#include <math.h>
#include <string.h>

typedef _Float16 half8 __attribute__((ext_vector_type(8)));
typedef _Float16 half4 __attribute__((ext_vector_type(4)));
typedef float floatx4 __attribute__((ext_vector_type(4)));
typedef float floatx16 __attribute__((ext_vector_type(16)));

#if defined(__has_builtin) && __has_builtin(__builtin_amdgcn_mfma_f32_16x16x16f16)
#define MFMA_PV(a, b, c) __builtin_amdgcn_mfma_f32_16x16x16f16((a), (b), (c), 0, 0, 0)
#else
__device__ __forceinline__ floatx4 mfma_pv_asm(half4 a, half4 b, floatx4 c) {
  floatx4 d;
  asm volatile("v_mfma_f32_16x16x16_f16 %0, %1, %2, %3"
               : "=v"(d) : "v"(a), "v"(b), "v"(c));
  return d;
}
#define MFMA_PV(a, b, c) mfma_pv_asm((a), (b), (c))
#endif

__device__ __forceinline__ floatx16 MFMA_S1(half4 a, half4 b, floatx16 c) {
#if defined(__has_builtin) && __has_builtin(__builtin_amdgcn_mfma_f32_32x32x8f16)
  return __builtin_amdgcn_mfma_f32_32x32x8f16(a, b, c, 0, 0, 0);
#else
  floatx16 d;
  asm volatile("v_mfma_f32_32x32x8_f16 %0, %1, %2, %3"
               : "=v"(d) : "v"(a), "v"(b), "v"(c));
  return d;
#endif
}

__device__ __forceinline__ floatx16 MFMA_S2(half8 a, half8 b, floatx16 c) {
#if defined(__has_builtin) && __has_builtin(__builtin_amdgcn_mfma_f32_32x32x16_f16)
  return __builtin_amdgcn_mfma_f32_32x32x16_f16(a, b, c, 0, 0, 0);
#else
  floatx16 d;
  asm volatile("v_mfma_f32_32x32x16_f16 %0, %1, %2, %3"
               : "=v"(d) : "v"(a), "v"(b), "v"(c));
  return d;
#endif
}

// ---------------------------------------------------------------------------
// LayerNorm -> f16 output
// ---------------------------------------------------------------------------
__global__ __launch_bounds__(256) void ln_kernel(const float* __restrict__ x,
                                                 const float* __restrict__ g,
                                                 const float* __restrict__ bv,
                                                 __half* __restrict__ h16) {
  int row = blockIdx.x, t = threadIdx.x;
  float v = x[(size_t)row * 256 + t];
  float s = v, q = v * v;
#pragma unroll
  for (int o = 32; o > 0; o >>= 1) {
    s += __shfl_xor(s, o);
    q += __shfl_xor(q, o);
  }
  __shared__ float ss[4], qq[4];
  int w = t >> 6, l = t & 63;
  if (l == 0) { ss[w] = s; qq[w] = q; }
  __syncthreads();
  s = ss[0] + ss[1] + ss[2] + ss[3];
  q = qq[0] + qq[1] + qq[2] + qq[3];
  float mu = s * (1.f / 256.f);
  float var = q * (1.f / 256.f) - mu * mu;
  float inv = rsqrtf(var + 1e-5f);
  h16[(size_t)row * 256 + t] = __float2half_rn((v - mu) * inv * g[t] + bv[t]);
}

// ---------------------------------------------------------------------------
// Setup: transpose weights to f16, build exact-GELU half2{g0,dg} lerp table
// (4 B/entry, step 1/64 on [-16,16)) + MFMA weight fragments. grid=1026x256.
// ---------------------------------------------------------------------------
__device__ __forceinline__ float gelu_exact(float z) {
  return 0.5f * z * (1.0f + erff(z * 0.70710678118654752f));
}
__device__ __forceinline__ unsigned int packh2(float a, float b) {
  __half2 h = __halves2half2(__float2half_rn(a), __float2half_rn(b));
  unsigned int u;
  memcpy(&u, &h, 4);
  return u;
}

__global__ __launch_bounds__(256) void setup_kernel(
    const float* __restrict__ w_qkv, const float* __restrict__ w_o,
    const float* __restrict__ w1, const float* __restrict__ b1,
    const float* __restrict__ w2,
    __half* __restrict__ wqT, __half* __restrict__ woT,
    unsigned int* __restrict__ gtabu, uint2* __restrict__ A1g,
    uint4* __restrict__ A2g) {
  int bx = blockIdx.x, t = threadIdx.x;
  if (bx < 768) {
    wqT[(size_t)bx * 256 + t] = __float2half_rn(w_qkv[(size_t)t * 768 + bx]);
  } else if (bx < 1024) {
    int n = bx - 768;
    woT[(size_t)n * 256 + t] = __float2half_rn(w_o[(size_t)t * 256 + n]);
  } else if (bx == 1024) {
#pragma unroll
    for (int s = 0; s < 8; s++) {
      int e = t * 8 + s;
      float z = -16.f + (float)e * (1.f / 64.f);
      float g0 = gelu_exact(z);
      float g1 = gelu_exact(z + (1.f / 64.f));
      gtabu[e] = packh2(g0, g1 - g0);
    }
  } else {
    // A1 frags: [2 hidden-blocks][64 lanes] -> 4 halves (K=8 stage-1 weights)
    if (t < 128) {
      int hb = t >> 6, l = t & 63;
      int hid = hb * 32 + (l & 31);
      float v[4];
#pragma unroll
      for (int e = 0; e < 4; e++) {
        int k = (l >> 5) * 4 + e;
        v[e] = (k < 5) ? w1[k * 64 + hid] : ((k == 5) ? b1[hid] : 0.f);
      }
      A1g[t] = make_uint2(packh2(v[0], v[1]), packh2(v[2], v[3]));
    }
    // A2 frags: [4 K-chunks][64 lanes] -> 8 halves (stage-2 w2^T, M rows 0-7)
    {
      int c = t >> 6, l = t & 63;
      int row = l & 31;
      float v[8];
#pragma unroll
      for (int e = 0; e < 8; e++) {
        int hid = c * 16 + (l >> 5) * 8 + e;
        v[e] = (row < 8) ? w2[hid * 8 + row] : 0.f;
      }
      A2g[t] = make_uint4(packh2(v[0], v[1]), packh2(v[2], v[3]),
                          packh2(v[4], v[5]), packh2(v[6], v[7]));
    }
  }
}

// ---------------------------------------------------------------------------
// f16 MFMA GEMM: C[M,N] f32 = A16[M,K] @ BT16[N,K]^T (+ bias). Wave = 16x16
// tile, K in chunks of 32. grid = (M/16 * N/16)/4 blocks x 256.
// ---------------------------------------------------------------------------
__global__ __launch_bounds__(256) void gemm16(
    const __half* __restrict__ A16, const __half* __restrict__ BT16,
    const float* __restrict__ bias, float* __restrict__ C,
    int ntn, int N, int K) {
  int wave = blockIdx.x * 4 + (threadIdx.x >> 6);
  int mt = wave / ntn, nt = wave - mt * ntn;
  int l = threadIdx.x & 63;
  int lg = l >> 4, li = l & 15;
  int m0 = mt * 16, n0 = nt * 16;
  floatx4 acc = {0.f, 0.f, 0.f, 0.f};
  for (int k0 = 0; k0 < K; k0 += 32) {
    half8 af = *(const half8*)((const _Float16*)A16 + (size_t)(m0 + li) * K + k0 + 8 * lg);
    half8 bf = *(const half8*)((const _Float16*)BT16 + (size_t)(n0 + li) * K + k0 + 8 * lg);
    acc = __builtin_amdgcn_mfma_f32_16x16x32_f16(af, bf, acc, 0, 0, 0);
  }
  float bb = bias ? bias[n0 + li] : 0.f;
#pragma unroll
  for (int r = 0; r < 4; r++) {
    C[(size_t)(m0 + 4 * lg + r) * N + n0 + li] = acc[r] + bb;
  }
}

// ---------------------------------------------------------------------------
// RoPE + split qkv (2048 x 768 f32) -> q,k,v FP16 in (B,H,N,D); fast trig
// ---------------------------------------------------------------------------
__global__ __launch_bounds__(256) void rope_split(const float* __restrict__ qkv,
                                                  __half* __restrict__ qo,
                                                  __half* __restrict__ ko,
                                                  __half* __restrict__ vo) {
  int row = blockIdx.x;
  int b = row >> 10, n = row & 1023;
  int t = threadIdx.x;
  int hh = t >> 5, d = t & 31;
  const float* base = qkv + (size_t)row * 768;
  float vv = base[512 + t];
  int f = d & 15;
  float inv_freq = exp2f((float)f * -0.8304820237218407f);  // 10000^(-f/16)
  float ang = (float)n * inv_freq;
  float sn, cs;
  __sincosf(ang, &sn, &cs);
  float q1 = base[hh * 32 + f], q2 = base[hh * 32 + f + 16];
  float k1 = base[256 + hh * 32 + f], k2 = base[256 + hh * 32 + f + 16];
  float qr = (d < 16) ? (q1 * cs - q2 * sn) : (q2 * cs + q1 * sn);
  float kr = (d < 16) ? (k1 * cs - k2 * sn) : (k2 * cs + k1 * sn);
  size_t oidx = ((size_t)(b * 8 + hh) * 1024 + n) * 32 + d;
  qo[oidx] = __float2half_rn(qr);
  ko[oidx] = __float2half_rn(kr);
  vo[oidx] = __float2half_rn(vv);
}

// ---------------------------------------------------------------------------
// Table GELU, f16 lerp: 4B half2{g0,dg} entries, step 1/64 on [-16,16).
// 7 VALU + 1 ds_read_b32 per eval; result is already _Float16 for the B-frag.
// ---------------------------------------------------------------------------
__device__ __forceinline__ _Float16 gelu_tab16(float z, const unsigned int* gt) {
  float tf = __builtin_amdgcn_fmed3f(fmaf(z, 64.f, 1024.f), 0.f, 2047.f);
  float fr = __builtin_amdgcn_fractf(tf);
  unsigned int e = gt[(unsigned int)tf];
  union { unsigned int u; _Float16 h[2]; } cv;
  cv.u = e;
  return (_Float16)(cv.h[0] + (_Float16)fr * cv.h[1]);
}
__device__ __forceinline__ unsigned int packf16x2(_Float16 a, _Float16 b) {
  union { unsigned int u; _Float16 h[2]; } cv;
  cv.h[0] = a; cv.h[1] = b;
  return cv.u;
}

// ---------------------------------------------------------------------------
// Relational bias via double MFMA + f16 table GELU -> rel[b][h][jrel][i] fp16.
// Block = (b, j): 4 waves x 8 i-tiles of 32. Per tile:
//   z[64][32] = 2x mfma_32x32x8(A1=w1^T, feats)      (f32 accum)
//   g = gelu_tab16(z)   (7 VALU + 4B LDS each, f16 out)
//   rel8[8][32] = 4x mfma_32x32x16(A2=w2^T, g-frag)  accumulated
// ---------------------------------------------------------------------------
__global__ __launch_bounds__(256) void rel_kernel(
    const float* __restrict__ coords, const float* __restrict__ vels,
    const unsigned int* __restrict__ gtabu, const uint2* __restrict__ A1g,
    const uint4* __restrict__ A2g, const float* __restrict__ b2,
    __half* __restrict__ rel, int j_base, int jspan) {
  __shared__ unsigned int gtab[2048];
  const int t = threadIdx.x;
  for (int e = t; e < 2048; e += 256) gtab[e] = gtabu[e];
  const int b = blockIdx.x / jspan;
  const int j = j_base + (blockIdx.x - b * jspan);
  const int wv = t >> 6;
  const int l = t & 63;
  const int li = l & 31, lh = l >> 5;

  uint2 a1u0 = A1g[l], a1u1 = A1g[64 + l];
  uint4 a2u0 = A2g[l], a2u1 = A2g[64 + l], a2u2 = A2g[128 + l], a2u3 = A2g[192 + l];
  float2 cj = *(const float2*)&coords[(size_t)(b * 1024 + j) * 2];
  float2 vj = *(const float2*)&vels[(size_t)(b * 1024 + j) * 2];
  float b2v0 = b2[4 * lh + 0], b2v1 = b2[4 * lh + 1];
  float b2v2 = b2[4 * lh + 2], b2v3 = b2[4 * lh + 3];
  const size_t hstride = (size_t)jspan * 1024;
  __syncthreads();

  for (int itg = 0; itg < 8; itg++) {
    const int i0 = (wv * 8 + itg) * 32;
    const int i = i0 + li;
    float2 ci = *(const float2*)&coords[(size_t)(b * 1024 + i) * 2];
    float2 vi = *(const float2*)&vels[(size_t)(b * 1024 + i) * 2];
    float dx0 = ci.x - cj.x, dx1 = ci.y - cj.y;
    float dv0 = vi.x - vj.x, dv1 = vi.y - vj.y;
    float dist = sqrtf(dx0 * dx0 + dx1 * dx1);
    // feats frag: pair=li, k-slots (lh*4 + 0..3): {dx0,dx1,dist,dv0 | dv1,1,0,0}
    half4 bf;
    bf[0] = lh ? (_Float16)dv1 : (_Float16)dx0;
    bf[1] = lh ? (_Float16)1.0f : (_Float16)dx1;
    bf[2] = lh ? (_Float16)0.0f : (_Float16)dist;
    bf[3] = lh ? (_Float16)0.0f : (_Float16)dv0;

    floatx16 zinit = {0.f};
    floatx16 acc = {0.f};

    // ---- hidden block 0 (hidden 0..31) ----
    {
      floatx16 z0 = MFMA_S1(*(half4*)&a1u0, bf, zinit);
      unsigned int u[8], p[8];
#pragma unroll
      for (int q = 0; q < 4; q++) {
        _Float16 g0 = gelu_tab16(z0[4 * q + 0], gtab);
        _Float16 g1 = gelu_tab16(z0[4 * q + 1], gtab);
        _Float16 g2 = gelu_tab16(z0[4 * q + 2], gtab);
        _Float16 g3 = gelu_tab16(z0[4 * q + 3], gtab);
        u[2 * q] = packf16x2(g0, g1);
        u[2 * q + 1] = packf16x2(g2, g3);
      }
#pragma unroll
      for (int e = 0; e < 8; e++) p[e] = __shfl_xor(u[e], 32);
#pragma unroll
      for (int cc = 0; cc < 2; cc++) {
        const int q = 2 * cc, qq = q + 1;
        uint4 bw;
        bw.x = lh ? p[2 * qq] : u[2 * q];
        bw.y = lh ? p[2 * qq + 1] : u[2 * q + 1];
        bw.z = lh ? u[2 * qq] : p[2 * q];
        bw.w = lh ? u[2 * qq + 1] : p[2 * q + 1];
        acc = MFMA_S2(cc == 0 ? *(half8*)&a2u0 : *(half8*)&a2u1,
                      *(half8*)&bw, acc);
      }
    }
    // ---- hidden block 1 (hidden 32..63) ----
    {
      floatx16 z1 = MFMA_S1(*(half4*)&a1u1, bf, zinit);
      unsigned int u[8], p[8];
#pragma unroll
      for (int q = 0; q < 4; q++) {
        _Float16 g0 = gelu_tab16(z1[4 * q + 0], gtab);
        _Float16 g1 = gelu_tab16(z1[4 * q + 1], gtab);
        _Float16 g2 = gelu_tab16(z1[4 * q + 2], gtab);
        _Float16 g3 = gelu_tab16(z1[4 * q + 3], gtab);
        u[2 * q] = packf16x2(g0, g1);
        u[2 * q + 1] = packf16x2(g2, g3);
      }
#pragma unroll
      for (int e = 0; e < 8; e++) p[e] = __shfl_xor(u[e], 32);
#pragma unroll
      for (int cc = 0; cc < 2; cc++) {
        const int q = 2 * cc, qq = q + 1;
        uint4 bw;
        bw.x = lh ? p[2 * qq] : u[2 * q];
        bw.y = lh ? p[2 * qq + 1] : u[2 * q + 1];
        bw.z = lh ? u[2 * qq] : p[2 * q];
        bw.w = lh ? u[2 * qq + 1] : p[2 * q + 1];
        acc = MFMA_S2(cc == 0 ? *(half8*)&a2u2 : *(half8*)&a2u3,
                      *(half8*)&bw, acc);
      }
    }
    // epilogue: heads 4*lh + 0..3 live in acc[0..3]
    size_t base = ((size_t)(b * 8) * jspan + (size_t)(j - j_base)) * 1024 + i;
    rel[base + (size_t)(4 * lh + 0) * hstride] = __float2half_rn(acc[0] + b2v0);
    rel[base + (size_t)(4 * lh + 1) * hstride] = __float2half_rn(acc[1] + b2v1);
    rel[base + (size_t)(4 * lh + 2) * hstride] = __float2half_rn(acc[2] + b2v2);
    rel[base + (size_t)(4 * lh + 3) * hstride] = __float2half_rn(acc[3] + b2v3);
  }
}

// ---------------------------------------------------------------------------
// MFMA flash attention (unchanged, verified).
// ---------------------------------------------------------------------------
__global__ __launch_bounds__(256) void attn_mfma(
    const __half* __restrict__ qh, const __half* __restrict__ kh,
    const __half* __restrict__ vh, const __half* __restrict__ rel,
    int j_base, int jspan, int js_force,
    float* __restrict__ Opart, float* __restrict__ ml) {
  const int task = blockIdx.x * 4 + (threadIdx.x >> 6);
  int js, it, h, b;
  if (js_force >= 0) {
    js = js_force; it = task & 63; h = (task >> 6) & 7; b = task >> 9;
  } else {
    js = task & 3; it = (task >> 2) & 63; h = (task >> 8) & 7; b = task >> 11;
  }
  const int lane = threadIdx.x & 63;
  const int lg = lane >> 4;
  const int li = lane & 15;
  const int i0 = it * 16;
  const size_t bh = (size_t)(b * 8 + h) * 1024;
  const float scale = 0.17677669529663687f;

  const half8 qf = *(const half8*)((const _Float16*)qh + (bh + i0 + li) * 32 + 8 * lg);

  floatx4 accLo = {0.f, 0.f, 0.f, 0.f};
  floatx4 accHi = {0.f, 0.f, 0.f, 0.f};
  float m_run = -3.0e38f, l_run = 0.f;

  for (int jt = js * 256; jt < js * 256 + 256; jt += 16) {
    half8 kf = *(const half8*)((const _Float16*)kh + (bh + jt + li) * 32 + 8 * lg);
    floatx4 zero = {0.f, 0.f, 0.f, 0.f};
    floatx4 st = __builtin_amdgcn_mfma_f32_16x16x32_f16(kf, qf, zero, 0, 0, 0);
    const __half* rrow = rel + ((size_t)(b * 8 + h) * jspan + (jt - j_base + 4 * lg)) * 1024 + i0 + li;
    float s0 = fmaf(st[0], scale, __half2float(rrow[0]));
    float s1 = fmaf(st[1], scale, __half2float(rrow[1024]));
    float s2 = fmaf(st[2], scale, __half2float(rrow[2048]));
    float s3 = fmaf(st[3], scale, __half2float(rrow[3072]));
    float tm = fmaxf(fmaxf(s0, s1), fmaxf(s2, s3));
    tm = fmaxf(tm, __shfl_xor(tm, 16));
    tm = fmaxf(tm, __shfl_xor(tm, 32));
    float nm = fmaxf(m_run, tm);
    float fc = __expf(m_run - nm);
    float p0 = __expf(s0 - nm);
    float p1 = __expf(s1 - nm);
    float p2 = __expf(s2 - nm);
    float p3 = __expf(s3 - nm);
    float ts = (p0 + p1) + (p2 + p3);
    ts += __shfl_xor(ts, 16);
    ts += __shfl_xor(ts, 32);
    l_run = l_run * fc + ts;
    m_run = nm;
    float fT0 = __shfl(fc, 4 * lg + 0);
    float fT1 = __shfl(fc, 4 * lg + 1);
    float fT2 = __shfl(fc, 4 * lg + 2);
    float fT3 = __shfl(fc, 4 * lg + 3);
    accLo[0] *= fT0; accHi[0] *= fT0;
    accLo[1] *= fT1; accHi[1] *= fT1;
    accLo[2] *= fT2; accHi[2] *= fT2;
    accLo[3] *= fT3; accHi[3] *= fT3;
    half4 pf;
    pf[0] = (_Float16)p0; pf[1] = (_Float16)p1;
    pf[2] = (_Float16)p2; pf[3] = (_Float16)p3;
    const _Float16* vb = (const _Float16*)vh + (bh + jt + 4 * lg) * 32 + li;
    half4 vf0, vf1;
    vf0[0] = vb[0];  vf0[1] = vb[32]; vf0[2] = vb[64]; vf0[3] = vb[96];
    vf1[0] = vb[16]; vf1[1] = vb[48]; vf1[2] = vb[80]; vf1[3] = vb[112];
    accLo = MFMA_PV(pf, vf0, accLo);
    accHi = MFMA_PV(pf, vf1, accHi);
  }
  size_t orow = (size_t)(b * 4 + js) * 1024 + i0 + 4 * lg;
#pragma unroll
  for (int r = 0; r < 4; r++) {
    float* op = Opart + (orow + r) * 256 + h * 32 + li;
    op[0] = accLo[r];
    op[16] = accHi[r];
  }
  if (lane < 16) {
    ((float2*)ml)[((size_t)(b * 4 + js) * 1024 + i0 + lane) * 8 + h] =
        make_float2(m_run, l_run);
  }
}

// ---------------------------------------------------------------------------
// Combine j-split partials -> attn16 (f16, feeds the out-proj MFMA GEMM)
// ---------------------------------------------------------------------------
__global__ __launch_bounds__(256) void combine_kernel(
    const float* __restrict__ Opart, const float* __restrict__ ml,
    __half* __restrict__ attn16) {
  int b = blockIdx.x >> 7, ig = blockIdx.x & 127;
  int i0 = ig * 8;
  int t = threadIdx.x, hh = t >> 5;
#pragma unroll
  for (int i = 0; i < 8; i++) {
    float2 mls[4];
    float M = -1e30f;
#pragma unroll
    for (int js = 0; js < 4; js++) {
      mls[js] = ((const float2*)ml)[(((size_t)(b * 4 + js) * 1024) + i0 + i) * 8 + hh];
      M = fmaxf(M, mls[js].x);
    }
    float L = 0.f, Ov = 0.f;
#pragma unroll
    for (int js = 0; js < 4; js++) {
      float w = __expf(mls[js].x - M);
      L += mls[js].y * w;
      Ov += Opart[(((size_t)(b * 4 + js) * 1024) + i0 + i) * 256 + t] * w;
    }
    attn16[((size_t)b * 1024 + i0 + i) * 256 + t] = __float2half_rn(Ov / L);
  }
}

// ---------------------------------------------------------------------------
extern "C" void kernel_launch(void* const* d_in, const int* in_sizes, int n_in,
                              void* d_out, int out_size, void* d_ws, size_t ws_size,
                              hipStream_t stream) {
  const float* x      = (const float*)d_in[0];
  const float* coords = (const float*)d_in[1];
  const float* vels   = (const float*)d_in[2];
  const float* ln_g   = (const float*)d_in[3];
  const float* ln_b   = (const float*)d_in[4];
  const float* w_qkv  = (const float*)d_in[5];
  const float* w_o    = (const float*)d_in[6];
  const float* b_o    = (const float*)d_in[7];
  const float* w1     = (const float*)d_in[8];
  const float* b1     = (const float*)d_in[9];
  const float* w2     = (const float*)d_in[10];
  const float* b2     = (const float*)d_in[11];
  float* out = (float*)d_out;

  // ws layout (bytes):
  //  [0, 8Mi)        Opart f32 (written by attn, after qkv is dead)
  //  [2Mi, 8Mi)      qkv f32 (dead after rope)
  //  [8Mi, +545KB)   wqT f16 | woT f16 | gtab(u32) | A1 | A2
  //  [9Mi, 10Mi)     h16 (ln out) -> overwritten by qh after qkv gemm
  //  [10Mi,11Mi) kh  [11Mi,12Mi) vh  [12Mi,13Mi) attn16
  //  [13Mi, 45Mi)    rel f16 full (chunk fallback: 8Mi)
  char* wsb = (char*)d_ws;
  float* Opart = (float*)wsb;
  float* qkv   = (float*)(wsb + 2097152);
  __half* wqT  = (__half*)(wsb + 8388608);
  __half* woT  = (__half*)(wsb + 8781824);
  unsigned int* gtab = (unsigned int*)(wsb + 8912896);
  uint2* A1g   = (uint2*)(wsb + 8929280);
  uint4* A2g   = (uint4*)(wsb + 8930304);
  __half* h16  = (__half*)(wsb + 9437184);
  __half* qh   = (__half*)(wsb + 9437184);
  __half* kh   = (__half*)(wsb + 10485760);
  __half* vh   = (__half*)(wsb + 11534336);
  __half* attn16 = (__half*)(wsb + 12582912);
  __half* relh = (__half*)(wsb + 13631488);
  float* ml    = (float*)d_out;  // scratch; final gemm fully rewrites d_out

  ln_kernel<<<2048, 256, 0, stream>>>(x, ln_g, ln_b, h16);
  setup_kernel<<<1026, 256, 0, stream>>>(w_qkv, w_o, w1, b1, w2,
                                         wqT, woT, gtab, A1g, A2g);
  gemm16<<<1536, 256, 0, stream>>>(h16, wqT, nullptr, qkv, 48, 768, 256);
  rope_split<<<2048, 256, 0, stream>>>(qkv, qh, kh, vh);

  const size_t full_bytes = 13631488ull + 33554432ull;  // 45 MiB
  if (ws_size >= full_bytes) {
    rel_kernel<<<2048, 256, 0, stream>>>(coords, vels, gtab, A1g, A2g, b2,
                                         relh, 0, 1024);
    attn_mfma<<<1024, 256, 0, stream>>>(qh, kh, vh, relh, 0, 1024, -1, Opart, ml);
  } else {
    for (int c = 0; c < 4; c++) {
      rel_kernel<<<512, 256, 0, stream>>>(coords, vels, gtab, A1g, A2g, b2,
                                          relh, c * 256, 256);
      attn_mfma<<<256, 256, 0, stream>>>(qh, kh, vh, relh, c * 256, 256, c,
                                         Opart, ml);
    }
  }
  combine_kernel<<<256, 256, 0, stream>>>(Opart, ml, attn16);
  gemm16<<<512, 256, 0, stream>>>(attn16, woT, b_o, out, 16, 256, 256);
}

// Round 11
// 107.552 us; speedup vs baseline: 6.2431x; 1.1421x over previous
//
#include <hip/hip_runtime.h>
#include <hip/hip_bf16.h>
#include <hip/hip_fp16.h>
#include <math.h>
#include <string.h>

typedef _Float16 half8 __attribute__((ext_vector_type(8)));
typedef _Float16 half4 __attribute__((ext_vector_type(4)));
typedef float floatx4 __attribute__((ext_vector_type(4)));
typedef float floatx16 __attribute__((ext_vector_type(16)));

#if defined(__has_builtin) && __has_builtin(__builtin_amdgcn_mfma_f32_16x16x16f16)
#define MFMA_PV(a, b, c) __builtin_amdgcn_mfma_f32_16x16x16f16((a), (b), (c), 0, 0, 0)
#else
__device__ __forceinline__ floatx4 mfma_pv_asm(half4 a, half4 b, floatx4 c) {
  floatx4 d;
  asm volatile("v_mfma_f32_16x16x16_f16 %0, %1, %2, %3"
               : "=v"(d) : "v"(a), "v"(b), "v"(c));
  return d;
}
#define MFMA_PV(a, b, c) mfma_pv_asm((a), (b), (c))
#endif

__device__ __forceinline__ floatx16 MFMA_S1(half4 a, half4 b, floatx16 c) {
#if defined(__has_builtin) && __has_builtin(__builtin_amdgcn_mfma_f32_32x32x8f16)
  return __builtin_amdgcn_mfma_f32_32x32x8f16(a, b, c, 0, 0, 0);
#else
  floatx16 d;
  asm volatile("v_mfma_f32_32x32x8_f16 %0, %1, %2, %3"
               : "=v"(d) : "v"(a), "v"(b), "v"(c));
  return d;
#endif
}

__device__ __forceinline__ floatx16 MFMA_S2(half8 a, half8 b, floatx16 c) {
#if defined(__has_builtin) && __has_builtin(__builtin_amdgcn_mfma_f32_32x32x16_f16)
  return __builtin_amdgcn_mfma_f32_32x32x16_f16(a, b, c, 0, 0, 0);
#else
  floatx16 d;
  asm volatile("v_mfma_f32_32x32x16_f16 %0, %1, %2, %3"
               : "=v"(d) : "v"(a), "v"(b), "v"(c));
  return d;
#endif
}

__device__ __forceinline__ float gelu_exact(float z) {
  return 0.5f * z * (1.0f + erff(z * 0.70710678118654752f));
}
__device__ __forceinline__ unsigned int packh2(float a, float b) {
  __half2 h = __halves2half2(__float2half_rn(a), __float2half_rn(b));
  unsigned int u;
  memcpy(&u, &h, 4);
  return u;
}

// ---------------------------------------------------------------------------
// Fused prep: bx<2048 -> LayerNorm row (f16 out); else weight transpose,
// GELU half2{g0,dg} lerp table, and MFMA weight fragments.
// A2 K-axis hidden permutation: hid = c*16 + (e&3) + 8*(e>>2) + 4*lh, which
// mirrors stage-1's C/D row layout -> stage-2 B-frag is in-lane (no shuffle).
// ---------------------------------------------------------------------------
__global__ __launch_bounds__(256) void prep_kernel(
    const float* __restrict__ x, const float* __restrict__ g,
    const float* __restrict__ bv, __half* __restrict__ h16,
    const float* __restrict__ w_qkv, const float* __restrict__ w_o,
    const float* __restrict__ w1, const float* __restrict__ b1,
    const float* __restrict__ w2,
    __half* __restrict__ wqT, __half* __restrict__ woT,
    unsigned int* __restrict__ gtabu, uint2* __restrict__ A1g,
    uint4* __restrict__ A2g) {
  int t = threadIdx.x;
  if (blockIdx.x < 2048) {
    int row = blockIdx.x;
    float v = x[(size_t)row * 256 + t];
    float s = v, q = v * v;
#pragma unroll
    for (int o = 32; o > 0; o >>= 1) {
      s += __shfl_xor(s, o);
      q += __shfl_xor(q, o);
    }
    __shared__ float ss[4], qq[4];
    int w = t >> 6, l = t & 63;
    if (l == 0) { ss[w] = s; qq[w] = q; }
    __syncthreads();
    s = ss[0] + ss[1] + ss[2] + ss[3];
    q = qq[0] + qq[1] + qq[2] + qq[3];
    float mu = s * (1.f / 256.f);
    float var = q * (1.f / 256.f) - mu * mu;
    float inv = rsqrtf(var + 1e-5f);
    h16[(size_t)row * 256 + t] = __float2half_rn((v - mu) * inv * g[t] + bv[t]);
    return;
  }
  int bx = blockIdx.x - 2048;
  if (bx < 768) {
    wqT[(size_t)bx * 256 + t] = __float2half_rn(w_qkv[(size_t)t * 768 + bx]);
  } else if (bx < 1024) {
    int n = bx - 768;
    woT[(size_t)n * 256 + t] = __float2half_rn(w_o[(size_t)t * 256 + n]);
  } else if (bx == 1024) {
#pragma unroll
    for (int s = 0; s < 8; s++) {
      int e = t * 8 + s;
      float z = -16.f + (float)e * (1.f / 64.f);
      float g0 = gelu_exact(z);
      float g1 = gelu_exact(z + (1.f / 64.f));
      gtabu[e] = packh2(g0, g1 - g0);
    }
  } else {
    // A1 frags: [2 hidden-blocks][64 lanes] -> 4 halves (K=8 stage-1 weights)
    if (t < 128) {
      int hb = t >> 6, l = t & 63;
      int hid = hb * 32 + (l & 31);
      float v[4];
#pragma unroll
      for (int e = 0; e < 4; e++) {
        int k = (l >> 5) * 4 + e;
        v[e] = (k < 5) ? w1[k * 64 + hid] : ((k == 5) ? b1[hid] : 0.f);
      }
      A1g[t] = make_uint2(packh2(v[0], v[1]), packh2(v[2], v[3]));
    }
    // A2 frags: [4 K-chunks][64 lanes], hid permuted to stage-1 D layout
    {
      int c = t >> 6, l = t & 63;
      int row = l & 31;
      int lh = l >> 5;
      float v[8];
#pragma unroll
      for (int e = 0; e < 8; e++) {
        int hid = c * 16 + (e & 3) + 8 * (e >> 2) + 4 * lh;
        v[e] = (row < 8) ? w2[hid * 8 + row] : 0.f;
      }
      A2g[t] = make_uint4(packh2(v[0], v[1]), packh2(v[2], v[3]),
                          packh2(v[4], v[5]), packh2(v[6], v[7]));
    }
  }
}

// ---------------------------------------------------------------------------
// f16 MFMA GEMM: C[M,N] f32 = A16[M,K] @ BT16[N,K]^T (+ bias). Wave = 16x16
// tile; two independent K-chunk accumulator chains (halve MFMA dep latency).
// ---------------------------------------------------------------------------
__global__ __launch_bounds__(256) void gemm16(
    const __half* __restrict__ A16, const __half* __restrict__ BT16,
    const float* __restrict__ bias, float* __restrict__ C,
    int ntn, int N, int K) {
  int wave = blockIdx.x * 4 + (threadIdx.x >> 6);
  int mt = wave / ntn, nt = wave - mt * ntn;
  int l = threadIdx.x & 63;
  int lg = l >> 4, li = l & 15;
  int m0 = mt * 16, n0 = nt * 16;
  floatx4 acc0 = {0.f, 0.f, 0.f, 0.f};
  floatx4 acc1 = {0.f, 0.f, 0.f, 0.f};
  const _Float16* ap = (const _Float16*)A16 + (size_t)(m0 + li) * K + 8 * lg;
  const _Float16* bp = (const _Float16*)BT16 + (size_t)(n0 + li) * K + 8 * lg;
  for (int k0 = 0; k0 < K; k0 += 64) {
    half8 a0 = *(const half8*)(ap + k0);
    half8 b0 = *(const half8*)(bp + k0);
    half8 a1 = *(const half8*)(ap + k0 + 32);
    half8 b1 = *(const half8*)(bp + k0 + 32);
    acc0 = __builtin_amdgcn_mfma_f32_16x16x32_f16(a0, b0, acc0, 0, 0, 0);
    acc1 = __builtin_amdgcn_mfma_f32_16x16x32_f16(a1, b1, acc1, 0, 0, 0);
  }
  float bb = bias ? bias[n0 + li] : 0.f;
#pragma unroll
  for (int r = 0; r < 4; r++) {
    C[(size_t)(m0 + 4 * lg + r) * N + n0 + li] = acc0[r] + acc1[r] + bb;
  }
}

// ---------------------------------------------------------------------------
// RoPE + split qkv (2048 x 768 f32) -> q,k,v FP16 in (B,H,N,D); fast trig
// ---------------------------------------------------------------------------
__global__ __launch_bounds__(256) void rope_split(const float* __restrict__ qkv,
                                                  __half* __restrict__ qo,
                                                  __half* __restrict__ ko,
                                                  __half* __restrict__ vo) {
  int row = blockIdx.x;
  int b = row >> 10, n = row & 1023;
  int t = threadIdx.x;
  int hh = t >> 5, d = t & 31;
  const float* base = qkv + (size_t)row * 768;
  float vv = base[512 + t];
  int f = d & 15;
  float inv_freq = exp2f((float)f * -0.8304820237218407f);  // 10000^(-f/16)
  float ang = (float)n * inv_freq;
  float sn, cs;
  __sincosf(ang, &sn, &cs);
  float q1 = base[hh * 32 + f], q2 = base[hh * 32 + f + 16];
  float k1 = base[256 + hh * 32 + f], k2 = base[256 + hh * 32 + f + 16];
  float qr = (d < 16) ? (q1 * cs - q2 * sn) : (q2 * cs + q1 * sn);
  float kr = (d < 16) ? (k1 * cs - k2 * sn) : (k2 * cs + k1 * sn);
  size_t oidx = ((size_t)(b * 8 + hh) * 1024 + n) * 32 + d;
  qo[oidx] = __float2half_rn(qr);
  ko[oidx] = __float2half_rn(kr);
  vo[oidx] = __float2half_rn(vv);
}

// ---------------------------------------------------------------------------
// Table GELU, f16 lerp: 4B half2{g0,dg} entries, step 1/64 on [-16,16).
// ---------------------------------------------------------------------------
__device__ __forceinline__ _Float16 gelu_tab16(float z, const unsigned int* gt) {
  float tf = __builtin_amdgcn_fmed3f(fmaf(z, 64.f, 1024.f), 0.f, 2047.f);
  float fr = __builtin_amdgcn_fractf(tf);
  unsigned int e = gt[(unsigned int)tf];
  union { unsigned int u; _Float16 h[2]; } cv;
  cv.u = e;
  return (_Float16)(cv.h[0] + (_Float16)fr * cv.h[1]);
}

// ---------------------------------------------------------------------------
// Relational bias via double MFMA + f16 table GELU -> rel[b][h][jrel][i] fp16.
// Block = (b, j): 4 waves x 8 i-tiles of 32. Per tile:
//   z[16] = mfma_32x32x8(A1, feats) per hidden-block (f32)
//   u[q]  = pack(gelu(z[2q]), gelu(z[2q+1]))  -- IN-LANE B-frag (A2 K-axis
//           permuted to stage-1's D layout; no cross-lane exchange)
//   acc  += mfma_32x32x16(A2_c, u[0..3]) ; += mfma_32x32x16(A2_c+1, u[4..7])
// ---------------------------------------------------------------------------
__global__ __launch_bounds__(256) void rel_kernel(
    const float* __restrict__ coords, const float* __restrict__ vels,
    const unsigned int* __restrict__ gtabu, const uint2* __restrict__ A1g,
    const uint4* __restrict__ A2g, const float* __restrict__ b2,
    __half* __restrict__ rel, int j_base, int jspan) {
  __shared__ unsigned int gtab[2048];
  const int t = threadIdx.x;
  for (int e = t; e < 2048; e += 256) gtab[e] = gtabu[e];
  const int b = blockIdx.x / jspan;
  const int j = j_base + (blockIdx.x - b * jspan);
  const int wv = t >> 6;
  const int l = t & 63;
  const int li = l & 31, lh = l >> 5;

  uint2 a1u0 = A1g[l], a1u1 = A1g[64 + l];
  uint4 a2u0 = A2g[l], a2u1 = A2g[64 + l], a2u2 = A2g[128 + l], a2u3 = A2g[192 + l];
  float2 cj = *(const float2*)&coords[(size_t)(b * 1024 + j) * 2];
  float2 vj = *(const float2*)&vels[(size_t)(b * 1024 + j) * 2];
  float b2v0 = b2[4 * lh + 0], b2v1 = b2[4 * lh + 1];
  float b2v2 = b2[4 * lh + 2], b2v3 = b2[4 * lh + 3];
  const size_t hstride = (size_t)jspan * 1024;
  __syncthreads();

  for (int itg = 0; itg < 8; itg++) {
    const int i0 = (wv * 8 + itg) * 32;
    const int i = i0 + li;
    float2 ci = *(const float2*)&coords[(size_t)(b * 1024 + i) * 2];
    float2 vi = *(const float2*)&vels[(size_t)(b * 1024 + i) * 2];
    float dx0 = ci.x - cj.x, dx1 = ci.y - cj.y;
    float dv0 = vi.x - vj.x, dv1 = vi.y - vj.y;
    float dist = sqrtf(dx0 * dx0 + dx1 * dx1);
    // feats frag: pair=li, k-slots (lh*4 + 0..3): {dx0,dx1,dist,dv0 | dv1,1,0,0}
    half4 bf;
    bf[0] = lh ? (_Float16)dv1 : (_Float16)dx0;
    bf[1] = lh ? (_Float16)1.0f : (_Float16)dx1;
    bf[2] = lh ? (_Float16)0.0f : (_Float16)dist;
    bf[3] = lh ? (_Float16)0.0f : (_Float16)dv0;

    floatx16 zinit = {0.f};
    floatx16 acc = {0.f};

    // ---- hidden block 0 (hiddens 0..31) ----
    {
      floatx16 z0 = MFMA_S1(*(half4*)&a1u0, bf, zinit);
      unsigned int u[8] __attribute__((aligned(16)));
#pragma unroll
      for (int q = 0; q < 8; q++) {
        _Float16 ga = gelu_tab16(z0[2 * q], gtab);
        _Float16 gb = gelu_tab16(z0[2 * q + 1], gtab);
        union { unsigned int uu; _Float16 h[2]; } cv;
        cv.h[0] = ga; cv.h[1] = gb;
        u[q] = cv.uu;
      }
      acc = MFMA_S2(*(half8*)&a2u0, *(half8*)&u[0], acc);
      acc = MFMA_S2(*(half8*)&a2u1, *(half8*)&u[4], acc);
    }
    // ---- hidden block 1 (hiddens 32..63) ----
    {
      floatx16 z1 = MFMA_S1(*(half4*)&a1u1, bf, zinit);
      unsigned int u[8] __attribute__((aligned(16)));
#pragma unroll
      for (int q = 0; q < 8; q++) {
        _Float16 ga = gelu_tab16(z1[2 * q], gtab);
        _Float16 gb = gelu_tab16(z1[2 * q + 1], gtab);
        union { unsigned int uu; _Float16 h[2]; } cv;
        cv.h[0] = ga; cv.h[1] = gb;
        u[q] = cv.uu;
      }
      acc = MFMA_S2(*(half8*)&a2u2, *(half8*)&u[0], acc);
      acc = MFMA_S2(*(half8*)&a2u3, *(half8*)&u[4], acc);
    }
    // epilogue: heads 4*lh + 0..3 live in acc[0..3]
    size_t base = ((size_t)(b * 8) * jspan + (size_t)(j - j_base)) * 1024 + i;
    rel[base + (size_t)(4 * lh + 0) * hstride] = __float2half_rn(acc[0] + b2v0);
    rel[base + (size_t)(4 * lh + 1) * hstride] = __float2half_rn(acc[1] + b2v1);
    rel[base + (size_t)(4 * lh + 2) * hstride] = __float2half_rn(acc[2] + b2v2);
    rel[base + (size_t)(4 * lh + 3) * hstride] = __float2half_rn(acc[3] + b2v3);
  }
}

// ---------------------------------------------------------------------------
// MFMA flash attention (unchanged, verified).
// ---------------------------------------------------------------------------
__global__ __launch_bounds__(256) void attn_mfma(
    const __half* __restrict__ qh, const __half* __restrict__ kh,
    const __half* __restrict__ vh, const __half* __restrict__ rel,
    int j_base, int jspan, int js_force,
    float* __restrict__ Opart, float* __restrict__ ml) {
  const int task = blockIdx.x * 4 + (threadIdx.x >> 6);
  int js, it, h, b;
  if (js_force >= 0) {
    js = js_force; it = task & 63; h = (task >> 6) & 7; b = task >> 9;
  } else {
    js = task & 3; it = (task >> 2) & 63; h = (task >> 8) & 7; b = task >> 11;
  }
  const int lane = threadIdx.x & 63;
  const int lg = lane >> 4;
  const int li = lane & 15;
  const int i0 = it * 16;
  const size_t bh = (size_t)(b * 8 + h) * 1024;
  const float scale = 0.17677669529663687f;

  const half8 qf = *(const half8*)((const _Float16*)qh + (bh + i0 + li) * 32 + 8 * lg);

  floatx4 accLo = {0.f, 0.f, 0.f, 0.f};
  floatx4 accHi = {0.f, 0.f, 0.f, 0.f};
  float m_run = -3.0e38f, l_run = 0.f;

  for (int jt = js * 256; jt < js * 256 + 256; jt += 16) {
    half8 kf = *(const half8*)((const _Float16*)kh + (bh + jt + li) * 32 + 8 * lg);
    floatx4 zero = {0.f, 0.f, 0.f, 0.f};
    floatx4 st = __builtin_amdgcn_mfma_f32_16x16x32_f16(kf, qf, zero, 0, 0, 0);
    const __half* rrow = rel + ((size_t)(b * 8 + h) * jspan + (jt - j_base + 4 * lg)) * 1024 + i0 + li;
    float s0 = fmaf(st[0], scale, __half2float(rrow[0]));
    float s1 = fmaf(st[1], scale, __half2float(rrow[1024]));
    float s2 = fmaf(st[2], scale, __half2float(rrow[2048]));
    float s3 = fmaf(st[3], scale, __half2float(rrow[3072]));
    float tm = fmaxf(fmaxf(s0, s1), fmaxf(s2, s3));
    tm = fmaxf(tm, __shfl_xor(tm, 16));
    tm = fmaxf(tm, __shfl_xor(tm, 32));
    float nm = fmaxf(m_run, tm);
    float fc = __expf(m_run - nm);
    float p0 = __expf(s0 - nm);
    float p1 = __expf(s1 - nm);
    float p2 = __expf(s2 - nm);
    float p3 = __expf(s3 - nm);
    float ts = (p0 + p1) + (p2 + p3);
    ts += __shfl_xor(ts, 16);
    ts += __shfl_xor(ts, 32);
    l_run = l_run * fc + ts;
    m_run = nm;
    float fT0 = __shfl(fc, 4 * lg + 0);
    float fT1 = __shfl(fc, 4 * lg + 1);
    float fT2 = __shfl(fc, 4 * lg + 2);
    float fT3 = __shfl(fc, 4 * lg + 3);
    accLo[0] *= fT0; accHi[0] *= fT0;
    accLo[1] *= fT1; accHi[1] *= fT1;
    accLo[2] *= fT2; accHi[2] *= fT2;
    accLo[3] *= fT3; accHi[3] *= fT3;
    half4 pf;
    pf[0] = (_Float16)p0; pf[1] = (_Float16)p1;
    pf[2] = (_Float16)p2; pf[3] = (_Float16)p3;
    const _Float16* vb = (const _Float16*)vh + (bh + jt + 4 * lg) * 32 + li;
    half4 vf0, vf1;
    vf0[0] = vb[0];  vf0[1] = vb[32]; vf0[2] = vb[64]; vf0[3] = vb[96];
    vf1[0] = vb[16]; vf1[1] = vb[48]; vf1[2] = vb[80]; vf1[3] = vb[112];
    accLo = MFMA_PV(pf, vf0, accLo);
    accHi = MFMA_PV(pf, vf1, accHi);
  }
  size_t orow = (size_t)(b * 4 + js) * 1024 + i0 + 4 * lg;
#pragma unroll
  for (int r = 0; r < 4; r++) {
    float* op = Opart + (orow + r) * 256 + h * 32 + li;
    op[0] = accLo[r];
    op[16] = accHi[r];
  }
  if (lane < 16) {
    ((float2*)ml)[((size_t)(b * 4 + js) * 1024 + i0 + lane) * 8 + h] =
        make_float2(m_run, l_run);
  }
}

// ---------------------------------------------------------------------------
// Combine j-split partials -> attn16 (f16, feeds the out-proj MFMA GEMM)
// ---------------------------------------------------------------------------
__global__ __launch_bounds__(256) void combine_kernel(
    const float* __restrict__ Opart, const float* __restrict__ ml,
    __half* __restrict__ attn16) {
  int b = blockIdx.x >> 7, ig = blockIdx.x & 127;
  int i0 = ig * 8;
  int t = threadIdx.x, hh = t >> 5;
#pragma unroll
  for (int i = 0; i < 8; i++) {
    float2 mls[4];
    float M = -1e30f;
#pragma unroll
    for (int js = 0; js < 4; js++) {
      mls[js] = ((const float2*)ml)[(((size_t)(b * 4 + js) * 1024) + i0 + i) * 8 + hh];
      M = fmaxf(M, mls[js].x);
    }
    float L = 0.f, Ov = 0.f;
#pragma unroll
    for (int js = 0; js < 4; js++) {
      float w = __expf(mls[js].x - M);
      L += mls[js].y * w;
      Ov += Opart[(((size_t)(b * 4 + js) * 1024) + i0 + i) * 256 + t] * w;
    }
    attn16[((size_t)b * 1024 + i0 + i) * 256 + t] = __float2half_rn(Ov / L);
  }
}

// ---------------------------------------------------------------------------
extern "C" void kernel_launch(void* const* d_in, const int* in_sizes, int n_in,
                              void* d_out, int out_size, void* d_ws, size_t ws_size,
                              hipStream_t stream) {
  const float* x      = (const float*)d_in[0];
  const float* coords = (const float*)d_in[1];
  const float* vels   = (const float*)d_in[2];
  const float* ln_g   = (const float*)d_in[3];
  const float* ln_b   = (const float*)d_in[4];
  const float* w_qkv  = (const float*)d_in[5];
  const float* w_o    = (const float*)d_in[6];
  const float* b_o    = (const float*)d_in[7];
  const float* w1     = (const float*)d_in[8];
  const float* b1     = (const float*)d_in[9];
  const float* w2     = (const float*)d_in[10];
  const float* b2     = (const float*)d_in[11];
  float* out = (float*)d_out;

  // ws layout (bytes):
  //  [0, 8Mi)        Opart f32 (written by attn, after qkv is dead)
  //  [2Mi, 8Mi)      qkv f32 (dead after rope)
  //  [8Mi, +545KB)   wqT f16 | woT f16 | gtab(u32) | A1 | A2
  //  [9Mi, 10Mi)     h16 (ln out) -> overwritten by qh after qkv gemm
  //  [10Mi,11Mi) kh  [11Mi,12Mi) vh  [12Mi,13Mi) attn16
  //  [13Mi, 45Mi)    rel f16 full (chunk fallback: 8Mi)
  char* wsb = (char*)d_ws;
  float* Opart = (float*)wsb;
  float* qkv   = (float*)(wsb + 2097152);
  __half* wqT  = (__half*)(wsb + 8388608);
  __half* woT  = (__half*)(wsb + 8781824);
  unsigned int* gtab = (unsigned int*)(wsb + 8912896);
  uint2* A1g   = (uint2*)(wsb + 8929280);
  uint4* A2g   = (uint4*)(wsb + 8930304);
  __half* h16  = (__half*)(wsb + 9437184);
  __half* qh   = (__half*)(wsb + 9437184);
  __half* kh   = (__half*)(wsb + 10485760);
  __half* vh   = (__half*)(wsb + 11534336);
  __half* attn16 = (__half*)(wsb + 12582912);
  __half* relh = (__half*)(wsb + 13631488);
  float* ml    = (float*)d_out;  // scratch; final gemm fully rewrites d_out

  prep_kernel<<<3074, 256, 0, stream>>>(x, ln_g, ln_b, h16, w_qkv, w_o,
                                        w1, b1, w2, wqT, woT, gtab, A1g, A2g);
  gemm16<<<1536, 256, 0, stream>>>(h16, wqT, nullptr, qkv, 48, 768, 256);
  rope_split<<<2048, 256, 0, stream>>>(qkv, qh, kh, vh);

  const size_t full_bytes = 13631488ull + 33554432ull;  // 45 MiB
  if (ws_size >= full_bytes) {
    rel_kernel<<<2048, 256, 0, stream>>>(coords, vels, gtab, A1g, A2g, b2,
                                         relh, 0, 1024);
    attn_mfma<<<1024, 256, 0, stream>>>(qh, kh, vh, relh, 0, 1024, -1, Opart, ml);
  } else {
    for (int c = 0; c < 4; c++) {
      rel_kernel<<<512, 256, 0, stream>>>(coords, vels, gtab, A1g, A2g, b2,
                                          relh, c * 256, 256);
      attn_mfma<<<256, 256, 0, stream>>>(qh, kh, vh, relh, c * 256, 256, c,
                                         Opart, ml);
    }
  }
  combine_kernel<<<256, 256, 0, stream>>>(Opart, ml, attn16);
  gemm16<<<512, 256, 0, stream>>>(attn16, woT, b_o, out, 16, 256, 256);
}